// Round 1
// baseline (1196.334 us; speedup 1.0000x reference)
//
#include <hip/hip_runtime.h>
#include <hip/hip_bf16.h>

typedef short bf16x8 __attribute__((ext_vector_type(8)));
typedef float f32x4  __attribute__((ext_vector_type(4)));

// ---------- problem constants ----------
// B=32, H=W=56, C=384, NH=12, WS=7, SS=3, DH=32, N=49, HID=1536
// tokens M = 32*56*56 = 100352; windows Bw = 2048; window-heads = 24576
static constexpr float SCALE = 0.17677669529663687f; // 32^-0.5

// map windowed-layout token t -> natural token index (b*3136 + h*56 + w)
// (same bijection serves LN1 gather and proj-epilogue scatter: h=(hs+3)%56)
__device__ __forceinline__ size_t win_to_nat(int t) {
  int win = t / 49; int n = t - win * 49;
  int bb = win >> 6; int wimg = win & 63;
  int hb = wimg >> 3, wb = wimg & 7;
  int nr = n / 7, nc = n - nr * 7;
  int hh = hb * 7 + nr + 3; if (hh >= 56) hh -= 56;
  int ww = wb * 7 + nc + 3; if (ww >= 56) ww -= 56;
  return (size_t)bb * 3136 + (size_t)hh * 56 + ww;
}

// ---------- weight transpose + cast: W (K x N, f32) -> Wt (N x K, bf16) ----------
__global__ __launch_bounds__(256)
void k_transpose(const float* __restrict__ W, __hip_bfloat16* __restrict__ Wt,
                 int K, int N, long tot) {
  long i = (long)blockIdx.x * 256 + threadIdx.x;
  if (i >= tot) return;
  long nn = i / K; long kk = i - nn * K;
  Wt[i] = __float2bfloat16(W[kk * N + nn]);
}

// ---------- LN1 + roll(-3,-3) + window partition; out bf16 windowed layout ----------
__global__ __launch_bounds__(256)
void k_ln1(const float* __restrict__ x, const float* __restrict__ gw,
           const float* __restrict__ bw, __hip_bfloat16* __restrict__ xw) {
  int lane = threadIdx.x & 63;
  int t = blockIdx.x * 4 + (threadIdx.x >> 6);
  size_t nt = win_to_nat(t);
  const float* xr = x + nt * 384;
  float4 a  = *(const float4*)(xr + lane * 4);
  float2 c2 = *(const float2*)(xr + 256 + lane * 2);
  float v[6] = {a.x, a.y, a.z, a.w, c2.x, c2.y};
  int c0 = lane * 4, c1 = 256 + lane * 2;
  int ch[6] = {c0, c0 + 1, c0 + 2, c0 + 3, c1, c1 + 1};
  float s = 0.f, q = 0.f;
#pragma unroll
  for (int i = 0; i < 6; i++) { s += v[i]; q += v[i] * v[i]; }
#pragma unroll
  for (int m = 1; m < 64; m <<= 1) { s += __shfl_xor(s, m); q += __shfl_xor(q, m); }
  float mean = s * (1.f / 384.f);
  float rstd = rsqrtf(q * (1.f / 384.f) - mean * mean + 1e-5f);
  __hip_bfloat16* o = xw + (size_t)t * 384;
#pragma unroll
  for (int i = 0; i < 6; i++)
    o[ch[i]] = __float2bfloat16((v[i] - mean) * rstd * gw[ch[i]] + bw[ch[i]]);
}

// ---------- double LN (ln2 eps=1e-5, ffln eps=1e-6) on x_res -> yln bf16 ----------
__global__ __launch_bounds__(256)
void k_ln2ff(const float* __restrict__ xres, const float* __restrict__ g2,
             const float* __restrict__ b2, const float* __restrict__ gf,
             const float* __restrict__ bf_, __hip_bfloat16* __restrict__ yln) {
  int lane = threadIdx.x & 63;
  int t = blockIdx.x * 4 + (threadIdx.x >> 6);
  const float* xr = xres + (size_t)t * 384;
  float4 a  = *(const float4*)(xr + lane * 4);
  float2 c2 = *(const float2*)(xr + 256 + lane * 2);
  float v[6] = {a.x, a.y, a.z, a.w, c2.x, c2.y};
  int c0 = lane * 4, c1 = 256 + lane * 2;
  int ch[6] = {c0, c0 + 1, c0 + 2, c0 + 3, c1, c1 + 1};
  float s = 0.f, q = 0.f;
#pragma unroll
  for (int i = 0; i < 6; i++) { s += v[i]; q += v[i] * v[i]; }
#pragma unroll
  for (int m = 1; m < 64; m <<= 1) { s += __shfl_xor(s, m); q += __shfl_xor(q, m); }
  float mean = s * (1.f / 384.f);
  float rstd = rsqrtf(q * (1.f / 384.f) - mean * mean + 1e-5f);
  float y1[6];
  s = 0.f; q = 0.f;
#pragma unroll
  for (int i = 0; i < 6; i++) {
    y1[i] = (v[i] - mean) * rstd * g2[ch[i]] + b2[ch[i]];
    s += y1[i]; q += y1[i] * y1[i];
  }
#pragma unroll
  for (int m = 1; m < 64; m <<= 1) { s += __shfl_xor(s, m); q += __shfl_xor(q, m); }
  float m2 = s * (1.f / 384.f);
  float r2 = rsqrtf(q * (1.f / 384.f) - m2 * m2 + 1e-6f);
  __hip_bfloat16* o = yln + (size_t)t * 384;
#pragma unroll
  for (int i = 0; i < 6; i++)
    o[ch[i]] = __float2bfloat16((y1[i] - m2) * r2 * gf[ch[i]] + bf_[ch[i]]);
}

// ---------- templated bf16 MFMA GEMM: C(M,N) = A(M,K) @ Wt(N,K)^T + bias ----------
enum { EPI_QKV = 0, EPI_PROJ = 1, EPI_FF1 = 2, EPI_FF2 = 3 };

template <int EPI>
__global__ __launch_bounds__(256)
void k_gemm(const __hip_bfloat16* __restrict__ A, const __hip_bfloat16* __restrict__ Wt,
            const float* __restrict__ bias, int K, int N,
            const float* __restrict__ aux,        // PROJ: x; FF2: x_res
            float* __restrict__ out_f,            // PROJ: x_res; FF2: final out
            __hip_bfloat16* __restrict__ out_b) { // QKV: q base; FF1: hbuf
  __shared__ __hip_bfloat16 As[128][40];
  __shared__ __hip_bfloat16 Bs[128][40];
  int tid = threadIdx.x;
  int lane = tid & 63, wave = tid >> 6;
  int wr = wave >> 1, wc = wave & 1;
  int g = lane >> 4, r16 = lane & 15;
  int rowBlk = blockIdx.x * 128;
  int colBlk = blockIdx.y * 128;
  const __hip_bfloat16* Abase = A + (size_t)rowBlk * K;
  const __hip_bfloat16* Wbase = Wt + (size_t)colBlk * K;

  f32x4 acc[4][4] = {};
  for (int k0 = 0; k0 < K; k0 += 32) {
    __syncthreads();
#pragma unroll
    for (int i = 0; i < 2; i++) {
      int vv = tid * 2 + i;
      int row = vv >> 2, co = (vv & 3) * 8;
      *(int4*)(&As[row][co]) = *(const int4*)(Abase + (size_t)row * K + k0 + co);
      *(int4*)(&Bs[row][co]) = *(const int4*)(Wbase + (size_t)row * K + k0 + co);
    }
    __syncthreads();
    bf16x8 af[4], bfr[4];
#pragma unroll
    for (int mi = 0; mi < 4; mi++) af[mi] = *(const bf16x8*)(&As[wr * 64 + mi * 16 + r16][g * 8]);
#pragma unroll
    for (int ni = 0; ni < 4; ni++) bfr[ni] = *(const bf16x8*)(&Bs[wc * 64 + ni * 16 + r16][g * 8]);
#pragma unroll
    for (int mi = 0; mi < 4; mi++)
#pragma unroll
      for (int ni = 0; ni < 4; ni++)
        acc[mi][ni] = __builtin_amdgcn_mfma_f32_16x16x32_bf16(af[mi], bfr[ni], acc[mi][ni], 0, 0, 0);
  }

#pragma unroll
  for (int mi = 0; mi < 4; mi++) {
#pragma unroll
    for (int rr = 0; rr < 4; rr++) {
      int row = rowBlk + wr * 64 + mi * 16 + g * 4 + rr;
      int winr = 0, nn = 0; size_t nt = 0;
      if constexpr (EPI == EPI_QKV) { winr = row / 49; nn = row - winr * 49; }
      if constexpr (EPI == EPI_PROJ) { nt = win_to_nat(row); }
#pragma unroll
      for (int ni = 0; ni < 4; ni++) {
        int col = colBlk + wc * 64 + ni * 16 + r16;
        float val = acc[mi][ni][rr] + bias[col];
        if constexpr (EPI == EPI_QKV) {
          int which = col / 384; int rem = col - which * 384;
          int hh = rem >> 5, dd = rem & 31;
          size_t off = (((size_t)winr * 12 + hh) * 49 + nn) * 32 + dd;
          out_b[(size_t)which * 38535168u + off] = __float2bfloat16(val);
        } else if constexpr (EPI == EPI_PROJ) {
          float r = val + aux[nt * 384 + col];
          out_f[nt * 384 + col] = r;
        } else if constexpr (EPI == EPI_FF1) {
          float ge = 0.5f * val * (1.f + erff(val * 0.70710678118f));
          out_b[(size_t)row * 1536 + col] = __float2bfloat16(ge);
        } else {
          out_f[(size_t)row * 384 + col] = val + aux[(size_t)row * 384 + col];
        }
      }
    }
  }
}

// ---------- windowed attention: 1 wave per (window, head) ----------
__global__ __launch_bounds__(256)
void k_attn(const __hip_bfloat16* __restrict__ q, const __hip_bfloat16* __restrict__ k,
            const __hip_bfloat16* __restrict__ v, const float* __restrict__ rpb,
            __hip_bfloat16* __restrict__ o) {
  __shared__ __hip_bfloat16 P[4][64][72];
  int tid = threadIdx.x;
  int lane = tid & 63, wave = tid >> 6;
  int g = lane >> 4, r16 = lane & 15;
  int gid = blockIdx.x * 4 + wave;              // 0..24575 window-heads
  int wi = gid / 12, h = gid - (gid / 12) * 12;
  int wimg = wi & 63;
  int hb = wimg >> 3, wb = wimg & 7;
  size_t base = ((size_t)wi * 12 + h) * (49 * 32);
  const __hip_bfloat16* qb = q + base;
  const __hip_bfloat16* kb = k + base;
  const __hip_bfloat16* vb = v + base;

  bf16x8 zf = {0, 0, 0, 0, 0, 0, 0, 0};
  bf16x8 qf[4], kf[4];
#pragma unroll
  for (int mi = 0; mi < 4; mi++) {
    int row = mi * 16 + r16;
    qf[mi] = (row < 49) ? *(const bf16x8*)(qb + row * 32 + g * 8) : zf;
    kf[mi] = (row < 49) ? *(const bf16x8*)(kb + row * 32 + g * 8) : zf;
  }
  f32x4 fz = {0.f, 0.f, 0.f, 0.f};
  f32x4 S[4][4];
#pragma unroll
  for (int mi = 0; mi < 4; mi++)
#pragma unroll
    for (int ni = 0; ni < 4; ni++)
      S[mi][ni] = __builtin_amdgcn_mfma_f32_16x16x32_bf16(qf[mi], kf[ni], fz, 0, 0, 0);

  // per-lane key-column precompute (col = ni*16 + r16)
  int kiA[4], kjA[4], rkA[4], cvA[4];
#pragma unroll
  for (int ni = 0; ni < 4; ni++) {
    int col = ni * 16 + r16;
    cvA[ni] = (col < 49);
    int ki = col / 7, kj = col - (col / 7) * 7;
    kiA[ni] = ki; kjA[ni] = kj;
    int hg = hb * 7 + ki, wg = wb * 7 + kj;
    int rh = (hg < 49) ? 0 : ((hg < 53) ? 1 : 2);
    int rw = (wg < 49) ? 0 : ((wg < 53) ? 1 : 2);
    rkA[ni] = rh * 3 + rw;
  }

  // softmax over keys, write P (bf16) to LDS
#pragma unroll
  for (int mi = 0; mi < 4; mi++) {
#pragma unroll
    for (int rr = 0; rr < 4; rr++) {
      int row = mi * 16 + g * 4 + rr;
      float sv[4];
      float mx = -1e30f;
      int qi = row / 7, qj = row - (row / 7) * 7;
      int hgq = hb * 7 + qi, wgq = wb * 7 + qj;
      int rhq = (hgq < 49) ? 0 : ((hgq < 53) ? 1 : 2);
      int rwq = (wgq < 49) ? 0 : ((wgq < 53) ? 1 : 2);
      int rq = rhq * 3 + rwq;
#pragma unroll
      for (int ni = 0; ni < 4; ni++) {
        float s = -1e30f;
        if (row < 49 && cvA[ni]) {
          int idx = (qi - kiA[ni] + 6) * 13 + (qj - kjA[ni] + 6);
          float maskv = (rq != rkA[ni]) ? -100.f : 0.f;
          s = S[mi][ni][rr] * SCALE + rpb[idx * 12 + h] + maskv;
        }
        sv[ni] = s;
        mx = fmaxf(mx, s);
      }
#pragma unroll
      for (int m = 1; m <= 8; m <<= 1) mx = fmaxf(mx, __shfl_xor(mx, m));
      float sum = 0.f;
#pragma unroll
      for (int ni = 0; ni < 4; ni++) {
        float p = __expf(sv[ni] - mx);
        sv[ni] = p; sum += p;
      }
#pragma unroll
      for (int m = 1; m <= 8; m <<= 1) sum += __shfl_xor(sum, m);
      float inv = 1.f / sum;
#pragma unroll
      for (int ni = 0; ni < 4; ni++)
        P[wave][row][ni * 16 + r16] = __float2bfloat16(sv[ni] * inv);
    }
  }

  // O = P @ V  (K = 64 in two 32-steps)
  f32x4 O[4][2] = {};
#pragma unroll
  for (int ks = 0; ks < 2; ks++) {
    bf16x8 pf[4];
#pragma unroll
    for (int mi = 0; mi < 4; mi++)
      pf[mi] = *(const bf16x8*)(&P[wave][mi * 16 + r16][ks * 32 + g * 8]);
#pragma unroll
    for (int ni = 0; ni < 2; ni++) {
      bf16x8 vf = zf;
#pragma unroll
      for (int j = 0; j < 8; j++) {
        int m = ks * 32 + g * 8 + j;
        if (m < 49) vf[j] = ((const short*)vb)[m * 32 + ni * 16 + r16];
      }
#pragma unroll
      for (int mi = 0; mi < 4; mi++)
        O[mi][ni] = __builtin_amdgcn_mfma_f32_16x16x32_bf16(pf[mi], vf, O[mi][ni], 0, 0, 0);
    }
  }

  // store (Bw, n, nh, dh) = (Bw, n, C) token-major bf16
#pragma unroll
  for (int mi = 0; mi < 4; mi++)
#pragma unroll
    for (int rr = 0; rr < 4; rr++) {
      int row = mi * 16 + g * 4 + rr;
      if (row < 49) {
#pragma unroll
        for (int ni = 0; ni < 2; ni++) {
          int col = ni * 16 + r16;
          o[(((size_t)wi * 49 + row) * 12 + h) * 32 + col] = __float2bfloat16(O[mi][ni][rr]);
        }
      }
    }
}

// ---------- host launch ----------
extern "C" void kernel_launch(void* const* d_in, const int* in_sizes, int n_in,
                              void* d_out, int out_size, void* d_ws, size_t ws_size,
                              hipStream_t stream) {
  const float* x      = (const float*)d_in[0];
  const float* ln1_g  = (const float*)d_in[1];
  const float* ln1_b  = (const float*)d_in[2];
  const float* qkv_w  = (const float*)d_in[3];
  const float* qkv_b  = (const float*)d_in[4];
  const float* proj_w = (const float*)d_in[5];
  const float* proj_b = (const float*)d_in[6];
  const float* rpb    = (const float*)d_in[7];
  const float* ln2_g  = (const float*)d_in[8];
  const float* ln2_b  = (const float*)d_in[9];
  const float* ffg    = (const float*)d_in[10];
  const float* ffb    = (const float*)d_in[11];
  const float* ff1_w  = (const float*)d_in[12];
  const float* ff1_b  = (const float*)d_in[13];
  const float* ff2_w  = (const float*)d_in[14];
  const float* ff2_b  = (const float*)d_in[15];
  float* out = (float*)d_out;

  char* ws = (char*)d_ws;
  // layout: [xw 77MB | q 77MB | k 77MB | v 77MB | x_res 154MB | yln 77MB | weights]
  // hbuf (308MB) aliases [xw|q|k|v] (dead by FF1); attn_out aliases xw (dead after QKV)
  __hip_bfloat16* xw     = (__hip_bfloat16*)ws;
  __hip_bfloat16* qbuf   = (__hip_bfloat16*)(ws + 77070336u);
  __hip_bfloat16* kbuf   = qbuf + 38535168u;
  __hip_bfloat16* vbuf   = kbuf + 38535168u;
  __hip_bfloat16* attn_o = xw;
  __hip_bfloat16* hbuf   = (__hip_bfloat16*)ws;
  float*          x_res  = (float*)(ws + 308281344u);
  __hip_bfloat16* yln    = (__hip_bfloat16*)(ws + 462422016u);
  __hip_bfloat16* qkv_wt = (__hip_bfloat16*)(ws + 539492352u);
  __hip_bfloat16* proj_wt = qkv_wt + 442368u;
  __hip_bfloat16* ff1_wt  = proj_wt + 147456u;
  __hip_bfloat16* ff2_wt  = ff1_wt + 589824u;

  // weight prep
  k_transpose<<<dim3((442368 + 255) / 256), dim3(256), 0, stream>>>(qkv_w, qkv_wt, 384, 1152, 442368);
  k_transpose<<<dim3((147456 + 255) / 256), dim3(256), 0, stream>>>(proj_w, proj_wt, 384, 384, 147456);
  k_transpose<<<dim3((589824 + 255) / 256), dim3(256), 0, stream>>>(ff1_w, ff1_wt, 384, 1536, 589824);
  k_transpose<<<dim3((589824 + 255) / 256), dim3(256), 0, stream>>>(ff2_w, ff2_wt, 1536, 384, 589824);

  // LN1 + shift + window partition
  k_ln1<<<dim3(25088), dim3(256), 0, stream>>>(x, ln1_g, ln1_b, xw);
  // QKV GEMM (100352 x 384) @ (384 x 1152)
  k_gemm<EPI_QKV><<<dim3(784, 9), dim3(256), 0, stream>>>(xw, qkv_wt, qkv_b, 384, 1152,
                                                          nullptr, nullptr, qbuf);
  // attention: 24576 window-heads, 4 per block
  k_attn<<<dim3(6144), dim3(256), 0, stream>>>(qbuf, kbuf, vbuf, rpb, attn_o);
  // proj GEMM + window reverse + residual -> x_res (f32, natural layout)
  k_gemm<EPI_PROJ><<<dim3(784, 3), dim3(256), 0, stream>>>(attn_o, proj_wt, proj_b, 384, 384,
                                                           x, x_res, nullptr);
  // LN2 + ffLN
  k_ln2ff<<<dim3(25088), dim3(256), 0, stream>>>(x_res, ln2_g, ln2_b, ffg, ffb, yln);
  // FF1 + gelu
  k_gemm<EPI_FF1><<<dim3(784, 12), dim3(256), 0, stream>>>(yln, ff1_wt, ff1_b, 384, 1536,
                                                           nullptr, nullptr, hbuf);
  // FF2 + residual -> out
  k_gemm<EPI_FF2><<<dim3(784, 3), dim3(256), 0, stream>>>(hbuf, ff2_wt, ff2_b, 1536, 384,
                                                          x_res, out, nullptr);
}

// Round 2
// 1067.062 us; speedup vs baseline: 1.1211x; 1.1211x over previous
//
#include <hip/hip_runtime.h>
#include <hip/hip_bf16.h>

typedef short bf16x8 __attribute__((ext_vector_type(8)));
typedef float f32x4  __attribute__((ext_vector_type(4)));

// ---------- problem constants ----------
// B=32, H=W=56, C=384, NH=12, WS=7, SS=3, DH=32, N=49, HID=1536
// tokens M = 32*56*56 = 100352; windows Bw = 2048; window-heads = 24576
static constexpr float SCALE = 0.17677669529663687f; // 32^-0.5

__device__ __forceinline__ void gload_lds16(const void* g, void* l) {
  __builtin_amdgcn_global_load_lds(
      (const __attribute__((address_space(1))) unsigned int*)g,
      (__attribute__((address_space(3))) unsigned int*)l, 16, 0, 0);
}

// map windowed-layout token t -> natural token index (b*3136 + h*56 + w)
__device__ __forceinline__ size_t win_to_nat(int t) {
  int win = t / 49; int n = t - win * 49;
  int bb = win >> 6; int wimg = win & 63;
  int hb = wimg >> 3, wb = wimg & 7;
  int nr = n / 7, nc = n - nr * 7;
  int hh = hb * 7 + nr + 3; if (hh >= 56) hh -= 56;
  int ww = wb * 7 + nc + 3; if (ww >= 56) ww -= 56;
  return (size_t)bb * 3136 + (size_t)hh * 56 + ww;
}

// ---------- weight transpose + cast: W (K x N, f32) -> Wt (N x K, bf16) ----------
__global__ __launch_bounds__(256)
void k_transpose(const float* __restrict__ W, __hip_bfloat16* __restrict__ Wt,
                 int K, int N, long tot) {
  long i = (long)blockIdx.x * 256 + threadIdx.x;
  if (i >= tot) return;
  long nn = i / K; long kk = i - nn * K;
  Wt[i] = __float2bfloat16(W[kk * N + nn]);
}

// ---------- LN1 + roll(-3,-3) + window partition; out bf16 windowed layout ----------
__global__ __launch_bounds__(256)
void k_ln1(const float* __restrict__ x, const float* __restrict__ gw,
           const float* __restrict__ bw, __hip_bfloat16* __restrict__ xw) {
  int lane = threadIdx.x & 63;
  int t = blockIdx.x * 4 + (threadIdx.x >> 6);
  size_t nt = win_to_nat(t);
  const float* xr = x + nt * 384;
  float4 a  = *(const float4*)(xr + lane * 4);
  float2 c2 = *(const float2*)(xr + 256 + lane * 2);
  float v[6] = {a.x, a.y, a.z, a.w, c2.x, c2.y};
  int c0 = lane * 4, c1 = 256 + lane * 2;
  int ch[6] = {c0, c0 + 1, c0 + 2, c0 + 3, c1, c1 + 1};
  float s = 0.f, q = 0.f;
#pragma unroll
  for (int i = 0; i < 6; i++) { s += v[i]; q += v[i] * v[i]; }
#pragma unroll
  for (int m = 1; m < 64; m <<= 1) { s += __shfl_xor(s, m); q += __shfl_xor(q, m); }
  float mean = s * (1.f / 384.f);
  float rstd = rsqrtf(q * (1.f / 384.f) - mean * mean + 1e-5f);
  __hip_bfloat16* o = xw + (size_t)t * 384;
#pragma unroll
  for (int i = 0; i < 6; i++)
    o[ch[i]] = __float2bfloat16((v[i] - mean) * rstd * gw[ch[i]] + bw[ch[i]]);
}

// ---------- double LN (ln2 eps=1e-5, ffln eps=1e-6) on x_res -> yln bf16 ----------
__global__ __launch_bounds__(256)
void k_ln2ff(const float* __restrict__ xres, const float* __restrict__ g2,
             const float* __restrict__ b2, const float* __restrict__ gf,
             const float* __restrict__ bf_, __hip_bfloat16* __restrict__ yln) {
  int lane = threadIdx.x & 63;
  int t = blockIdx.x * 4 + (threadIdx.x >> 6);
  const float* xr = xres + (size_t)t * 384;
  float4 a  = *(const float4*)(xr + lane * 4);
  float2 c2 = *(const float2*)(xr + 256 + lane * 2);
  float v[6] = {a.x, a.y, a.z, a.w, c2.x, c2.y};
  int c0 = lane * 4, c1 = 256 + lane * 2;
  int ch[6] = {c0, c0 + 1, c0 + 2, c0 + 3, c1, c1 + 1};
  float s = 0.f, q = 0.f;
#pragma unroll
  for (int i = 0; i < 6; i++) { s += v[i]; q += v[i] * v[i]; }
#pragma unroll
  for (int m = 1; m < 64; m <<= 1) { s += __shfl_xor(s, m); q += __shfl_xor(q, m); }
  float mean = s * (1.f / 384.f);
  float rstd = rsqrtf(q * (1.f / 384.f) - mean * mean + 1e-5f);
  float y1[6];
  s = 0.f; q = 0.f;
#pragma unroll
  for (int i = 0; i < 6; i++) {
    y1[i] = (v[i] - mean) * rstd * g2[ch[i]] + b2[ch[i]];
    s += y1[i]; q += y1[i] * y1[i];
  }
#pragma unroll
  for (int m = 1; m < 64; m <<= 1) { s += __shfl_xor(s, m); q += __shfl_xor(q, m); }
  float m2 = s * (1.f / 384.f);
  float r2 = rsqrtf(q * (1.f / 384.f) - m2 * m2 + 1e-6f);
  __hip_bfloat16* o = yln + (size_t)t * 384;
#pragma unroll
  for (int i = 0; i < 6; i++)
    o[ch[i]] = __float2bfloat16((y1[i] - m2) * r2 * gf[ch[i]] + bf_[ch[i]]);
}

// ---------- m97-style bf16 MFMA GEMM: C(M,N) = A(M,K) @ Wt(N,K)^T + bias ----------
// 128x128 tile, BK=32, global_load_lds(16B) staging, linear LDS, 1D grid with
// bijective XCD swizzle + col-fastest decomposition for L2 A/B reuse.
enum { EPI_QKV = 0, EPI_PROJ = 1, EPI_FF1 = 2, EPI_FF2 = 3 };

template <int EPI>
__global__ __launch_bounds__(256)
void k_gemm(const __hip_bfloat16* __restrict__ A, const __hip_bfloat16* __restrict__ Wt,
            const float* __restrict__ bias, int K, int nCol, int cpx,
            const float* __restrict__ aux,        // PROJ: x; FF2: x_res
            float* __restrict__ out_f,            // PROJ: x_res; FF2: final out
            __hip_bfloat16* __restrict__ out_b) { // QKV: q base; FF1: hbuf
  __shared__ __hip_bfloat16 As[128 * 32];
  __shared__ __hip_bfloat16 Bs[128 * 32];
  int tid = threadIdx.x;
  int lane = tid & 63, wave = tid >> 6;
  int wr = wave >> 1, wc = wave & 1;
  int g = lane >> 4, r16 = lane & 15;

  // XCD-aware swizzle: each of 8 XCDs gets a contiguous wg chunk (nwg % 8 == 0)
  int bid = blockIdx.x;
  int wg = (bid & 7) * cpx + (bid >> 3);
  int rB = wg / nCol;
  int rowBlk = rB * 128;
  int colBlk = (wg - rB * nCol) * 128;

  // staging addresses: thread t loads 16B at A[rowBlk + t/4][(t&3)*8 + k0]
  const __hip_bfloat16* Ab = A + (size_t)(rowBlk + (tid >> 2)) * K + (tid & 3) * 8;
  const __hip_bfloat16* Wb = Wt + (size_t)(colBlk + (tid >> 2)) * K + (tid & 3) * 8;
  size_t K64 = (size_t)K * 64;
  __hip_bfloat16* ldsA = &As[wave * 512];   // wave-uniform base; HW adds lane*16B
  __hip_bfloat16* ldsB = &Bs[wave * 512];

  f32x4 acc[4][4] = {};
  for (int k0 = 0; k0 < K; k0 += 32) {
    gload_lds16(Ab + k0,       ldsA);
    gload_lds16(Ab + K64 + k0, ldsA + 2048);
    gload_lds16(Wb + k0,       ldsB);
    gload_lds16(Wb + K64 + k0, ldsB + 2048);
    __syncthreads();   // drains vmcnt(0) then barrier
    bf16x8 af[4], bfr[4];
#pragma unroll
    for (int mi = 0; mi < 4; mi++)
      af[mi] = *(const bf16x8*)(&As[(wr * 64 + mi * 16 + r16) * 32 + g * 8]);
#pragma unroll
    for (int ni = 0; ni < 4; ni++)
      bfr[ni] = *(const bf16x8*)(&Bs[(wc * 64 + ni * 16 + r16) * 32 + g * 8]);
#pragma unroll
    for (int mi = 0; mi < 4; mi++)
#pragma unroll
      for (int ni = 0; ni < 4; ni++)
        acc[mi][ni] = __builtin_amdgcn_mfma_f32_16x16x32_bf16(af[mi], bfr[ni], acc[mi][ni], 0, 0, 0);
    __syncthreads();
  }

#pragma unroll
  for (int mi = 0; mi < 4; mi++) {
#pragma unroll
    for (int rr = 0; rr < 4; rr++) {
      int row = rowBlk + wr * 64 + mi * 16 + g * 4 + rr;
      int winr = 0, nn = 0; size_t nt = 0;
      if constexpr (EPI == EPI_QKV) { winr = row / 49; nn = row - winr * 49; }
      if constexpr (EPI == EPI_PROJ) { nt = win_to_nat(row); }
#pragma unroll
      for (int ni = 0; ni < 4; ni++) {
        int col = colBlk + wc * 64 + ni * 16 + r16;
        float val = acc[mi][ni][rr] + bias[col];
        if constexpr (EPI == EPI_QKV) {
          int which = col / 384; int rem = col - which * 384;
          int hh = rem >> 5, dd = rem & 31;
          size_t off = (((size_t)winr * 12 + hh) * 49 + nn) * 32 + dd;
          out_b[(size_t)which * 38535168u + off] = __float2bfloat16(val);
        } else if constexpr (EPI == EPI_PROJ) {
          float r = val + aux[nt * 384 + col];
          out_f[nt * 384 + col] = r;
        } else if constexpr (EPI == EPI_FF1) {
          float ge = 0.5f * val * (1.f + erff(val * 0.70710678118f));
          out_b[(size_t)row * 1536 + col] = __float2bfloat16(ge);
        } else {
          out_f[(size_t)row * 384 + col] = val + aux[(size_t)row * 384 + col];
        }
      }
    }
  }
}

// ---------- windowed attention: 1 wave per (window, head) ----------
__global__ __launch_bounds__(256)
void k_attn(const __hip_bfloat16* __restrict__ q, const __hip_bfloat16* __restrict__ k,
            const __hip_bfloat16* __restrict__ v, const float* __restrict__ rpb,
            __hip_bfloat16* __restrict__ o) {
  __shared__ __hip_bfloat16 P[4][64][72];
  int tid = threadIdx.x;
  int lane = tid & 63, wave = tid >> 6;
  int g = lane >> 4, r16 = lane & 15;
  int gid = blockIdx.x * 4 + wave;              // 0..24575 window-heads
  int wi = gid / 12, h = gid - (gid / 12) * 12;
  int wimg = wi & 63;
  int hb = wimg >> 3, wb = wimg & 7;
  size_t base = ((size_t)wi * 12 + h) * (49 * 32);
  const __hip_bfloat16* qb = q + base;
  const __hip_bfloat16* kb = k + base;
  const __hip_bfloat16* vb = v + base;

  bf16x8 zf = {0, 0, 0, 0, 0, 0, 0, 0};
  bf16x8 qf[4], kf[4];
#pragma unroll
  for (int mi = 0; mi < 4; mi++) {
    int row = mi * 16 + r16;
    qf[mi] = (row < 49) ? *(const bf16x8*)(qb + row * 32 + g * 8) : zf;
    kf[mi] = (row < 49) ? *(const bf16x8*)(kb + row * 32 + g * 8) : zf;
  }
  f32x4 fz = {0.f, 0.f, 0.f, 0.f};
  f32x4 S[4][4];
#pragma unroll
  for (int mi = 0; mi < 4; mi++)
#pragma unroll
    for (int ni = 0; ni < 4; ni++)
      S[mi][ni] = __builtin_amdgcn_mfma_f32_16x16x32_bf16(qf[mi], kf[ni], fz, 0, 0, 0);

  int kiA[4], kjA[4], rkA[4], cvA[4];
#pragma unroll
  for (int ni = 0; ni < 4; ni++) {
    int col = ni * 16 + r16;
    cvA[ni] = (col < 49);
    int ki = col / 7, kj = col - (col / 7) * 7;
    kiA[ni] = ki; kjA[ni] = kj;
    int hg = hb * 7 + ki, wg = wb * 7 + kj;
    int rh = (hg < 49) ? 0 : ((hg < 53) ? 1 : 2);
    int rw = (wg < 49) ? 0 : ((wg < 53) ? 1 : 2);
    rkA[ni] = rh * 3 + rw;
  }

#pragma unroll
  for (int mi = 0; mi < 4; mi++) {
#pragma unroll
    for (int rr = 0; rr < 4; rr++) {
      int row = mi * 16 + g * 4 + rr;
      float sv[4];
      float mx = -1e30f;
      int qi = row / 7, qj = row - (row / 7) * 7;
      int hgq = hb * 7 + qi, wgq = wb * 7 + qj;
      int rhq = (hgq < 49) ? 0 : ((hgq < 53) ? 1 : 2);
      int rwq = (wgq < 49) ? 0 : ((wgq < 53) ? 1 : 2);
      int rq = rhq * 3 + rwq;
#pragma unroll
      for (int ni = 0; ni < 4; ni++) {
        float s = -1e30f;
        if (row < 49 && cvA[ni]) {
          int idx = (qi - kiA[ni] + 6) * 13 + (qj - kjA[ni] + 6);
          float maskv = (rq != rkA[ni]) ? -100.f : 0.f;
          s = S[mi][ni][rr] * SCALE + rpb[idx * 12 + h] + maskv;
        }
        sv[ni] = s;
        mx = fmaxf(mx, s);
      }
#pragma unroll
      for (int m = 1; m <= 8; m <<= 1) mx = fmaxf(mx, __shfl_xor(mx, m));
      float sum = 0.f;
#pragma unroll
      for (int ni = 0; ni < 4; ni++) {
        float p = __expf(sv[ni] - mx);
        sv[ni] = p; sum += p;
      }
#pragma unroll
      for (int m = 1; m <= 8; m <<= 1) sum += __shfl_xor(sum, m);
      float inv = 1.f / sum;
#pragma unroll
      for (int ni = 0; ni < 4; ni++)
        P[wave][row][ni * 16 + r16] = __float2bfloat16(sv[ni] * inv);
    }
  }

  f32x4 O[4][2] = {};
#pragma unroll
  for (int ks = 0; ks < 2; ks++) {
    bf16x8 pf[4];
#pragma unroll
    for (int mi = 0; mi < 4; mi++)
      pf[mi] = *(const bf16x8*)(&P[wave][mi * 16 + r16][ks * 32 + g * 8]);
#pragma unroll
    for (int ni = 0; ni < 2; ni++) {
      bf16x8 vf = zf;
#pragma unroll
      for (int j = 0; j < 8; j++) {
        int m = ks * 32 + g * 8 + j;
        if (m < 49) vf[j] = ((const short*)vb)[m * 32 + ni * 16 + r16];
      }
#pragma unroll
      for (int mi = 0; mi < 4; mi++)
        O[mi][ni] = __builtin_amdgcn_mfma_f32_16x16x32_bf16(pf[mi], vf, O[mi][ni], 0, 0, 0);
    }
  }

#pragma unroll
  for (int mi = 0; mi < 4; mi++)
#pragma unroll
    for (int rr = 0; rr < 4; rr++) {
      int row = mi * 16 + g * 4 + rr;
      if (row < 49) {
#pragma unroll
        for (int ni = 0; ni < 2; ni++) {
          int col = ni * 16 + r16;
          o[(((size_t)wi * 49 + row) * 12 + h) * 32 + col] = __float2bfloat16(O[mi][ni][rr]);
        }
      }
    }
}

// ---------- host launch ----------
extern "C" void kernel_launch(void* const* d_in, const int* in_sizes, int n_in,
                              void* d_out, int out_size, void* d_ws, size_t ws_size,
                              hipStream_t stream) {
  const float* x      = (const float*)d_in[0];
  const float* ln1_g  = (const float*)d_in[1];
  const float* ln1_b  = (const float*)d_in[2];
  const float* qkv_w  = (const float*)d_in[3];
  const float* qkv_b  = (const float*)d_in[4];
  const float* proj_w = (const float*)d_in[5];
  const float* proj_b = (const float*)d_in[6];
  const float* rpb    = (const float*)d_in[7];
  const float* ln2_g  = (const float*)d_in[8];
  const float* ln2_b  = (const float*)d_in[9];
  const float* ffg    = (const float*)d_in[10];
  const float* ffb    = (const float*)d_in[11];
  const float* ff1_w  = (const float*)d_in[12];
  const float* ff1_b  = (const float*)d_in[13];
  const float* ff2_w  = (const float*)d_in[14];
  const float* ff2_b  = (const float*)d_in[15];
  float* out = (float*)d_out;

  char* ws = (char*)d_ws;
  // layout: [xw 77MB | q 77MB | k 77MB | v 77MB | x_res 154MB | yln 77MB | weights]
  // hbuf (308MB) aliases [xw|q|k|v] (dead by FF1); attn_out aliases xw (dead after QKV)
  __hip_bfloat16* xw     = (__hip_bfloat16*)ws;
  __hip_bfloat16* qbuf   = (__hip_bfloat16*)(ws + 77070336u);
  __hip_bfloat16* kbuf   = qbuf + 38535168u;
  __hip_bfloat16* vbuf   = kbuf + 38535168u;
  __hip_bfloat16* attn_o = xw;
  __hip_bfloat16* hbuf   = (__hip_bfloat16*)ws;
  float*          x_res  = (float*)(ws + 308281344u);
  __hip_bfloat16* yln    = (__hip_bfloat16*)(ws + 462422016u);
  __hip_bfloat16* qkv_wt = (__hip_bfloat16*)(ws + 539492352u);
  __hip_bfloat16* proj_wt = qkv_wt + 442368u;
  __hip_bfloat16* ff1_wt  = proj_wt + 147456u;
  __hip_bfloat16* ff2_wt  = ff1_wt + 589824u;

  // weight prep
  k_transpose<<<dim3((442368 + 255) / 256), dim3(256), 0, stream>>>(qkv_w, qkv_wt, 384, 1152, 442368);
  k_transpose<<<dim3((147456 + 255) / 256), dim3(256), 0, stream>>>(proj_w, proj_wt, 384, 384, 147456);
  k_transpose<<<dim3((589824 + 255) / 256), dim3(256), 0, stream>>>(ff1_w, ff1_wt, 384, 1536, 589824);
  k_transpose<<<dim3((589824 + 255) / 256), dim3(256), 0, stream>>>(ff2_w, ff2_wt, 1536, 384, 589824);

  // LN1 + shift + window partition
  k_ln1<<<dim3(25088), dim3(256), 0, stream>>>(x, ln1_g, ln1_b, xw);

  // QKV GEMM: M=100352, N=1152, K=384 -> nwg = 784*9 = 7056
  k_gemm<EPI_QKV><<<dim3(7056), dim3(256), 0, stream>>>(xw, qkv_wt, qkv_b, 384, 9, 7056 / 8,
                                                        nullptr, nullptr, qbuf);
  // attention: 24576 window-heads, 4 per block
  k_attn<<<dim3(6144), dim3(256), 0, stream>>>(qbuf, kbuf, vbuf, rpb, attn_o);
  // proj GEMM + window reverse + residual -> x_res: N=384 -> nwg = 784*3 = 2352
  k_gemm<EPI_PROJ><<<dim3(2352), dim3(256), 0, stream>>>(attn_o, proj_wt, proj_b, 384, 3, 2352 / 8,
                                                         x, x_res, nullptr);
  // LN2 + ffLN
  k_ln2ff<<<dim3(25088), dim3(256), 0, stream>>>(x_res, ln2_g, ln2_b, ffg, ffb, yln);
  // FF1 + gelu: N=1536 -> nwg = 784*12 = 9408
  k_gemm<EPI_FF1><<<dim3(9408), dim3(256), 0, stream>>>(yln, ff1_wt, ff1_b, 384, 12, 9408 / 8,
                                                        nullptr, nullptr, hbuf);
  // FF2 + residual -> out: K=1536, N=384 -> nwg = 2352
  k_gemm<EPI_FF2><<<dim3(2352), dim3(256), 0, stream>>>(hbuf, ff2_wt, ff2_b, 1536, 3, 2352 / 8,
                                                        x_res, out, nullptr);
}

// Round 3
// 1066.035 us; speedup vs baseline: 1.1222x; 1.0010x over previous
//
#include <hip/hip_runtime.h>
#include <hip/hip_bf16.h>

typedef short bf16x8 __attribute__((ext_vector_type(8)));
typedef float f32x4  __attribute__((ext_vector_type(4)));

// ---------- problem constants ----------
// B=32, H=W=56, C=384, NH=12, WS=7, SS=3, DH=32, N=49, HID=1536
static constexpr float SCALE = 0.17677669529663687f; // 32^-0.5

__device__ __forceinline__ void gload_lds16(const void* g, void* l) {
  __builtin_amdgcn_global_load_lds(
      (const __attribute__((address_space(1))) unsigned int*)g,
      (__attribute__((address_space(3))) unsigned int*)l, 16, 0, 0);
}

// map windowed-layout token t -> natural token index (b*3136 + h*56 + w)
__device__ __forceinline__ size_t win_to_nat(int t) {
  int win = t / 49; int n = t - win * 49;
  int bb = win >> 6; int wimg = win & 63;
  int hb = wimg >> 3, wb = wimg & 7;
  int nr = n / 7, nc = n - nr * 7;
  int hh = hb * 7 + nr + 3; if (hh >= 56) hh -= 56;
  int ww = wb * 7 + nc + 3; if (ww >= 56) ww -= 56;
  return (size_t)bb * 3136 + (size_t)hh * 56 + ww;
}

// ---------- LDS-tiled weight transpose+cast: W (K x N f32) -> Wt (N x K bf16) ----
// K, N multiples of 32. Coalesced reads AND writes.
__global__ __launch_bounds__(256)
void k_transpose(const float* __restrict__ W, __hip_bfloat16* __restrict__ Wt,
                 int K, int N) {
  __shared__ float tile[32][33];
  int tx = threadIdx.x & 31, ty = threadIdx.x >> 5;  // 32 x 8
  int tc = blockIdx.x, tr = blockIdx.y;              // col-tile (N), row-tile (K)
#pragma unroll
  for (int r = 0; r < 32; r += 8)
    tile[r + ty][tx] = W[(size_t)(tr * 32 + r + ty) * N + tc * 32 + tx];
  __syncthreads();
#pragma unroll
  for (int r = 0; r < 32; r += 8)
    Wt[(size_t)(tc * 32 + r + ty) * K + tr * 32 + tx] =
        __float2bfloat16(tile[tx][r + ty]);
}

// ---------- LN1 + roll(-3,-3) + window partition; out bf16 windowed layout ----------
__global__ __launch_bounds__(256)
void k_ln1(const float* __restrict__ x, const float* __restrict__ gw,
           const float* __restrict__ bw, __hip_bfloat16* __restrict__ xw) {
  int lane = threadIdx.x & 63;
  int t = blockIdx.x * 4 + (threadIdx.x >> 6);
  size_t nt = win_to_nat(t);
  const float* xr = x + nt * 384;
  float4 a  = *(const float4*)(xr + lane * 4);
  float2 c2 = *(const float2*)(xr + 256 + lane * 2);
  float v[6] = {a.x, a.y, a.z, a.w, c2.x, c2.y};
  int c0 = lane * 4, c1 = 256 + lane * 2;
  int ch[6] = {c0, c0 + 1, c0 + 2, c0 + 3, c1, c1 + 1};
  float s = 0.f, q = 0.f;
#pragma unroll
  for (int i = 0; i < 6; i++) { s += v[i]; q += v[i] * v[i]; }
#pragma unroll
  for (int m = 1; m < 64; m <<= 1) { s += __shfl_xor(s, m); q += __shfl_xor(q, m); }
  float mean = s * (1.f / 384.f);
  float rstd = rsqrtf(q * (1.f / 384.f) - mean * mean + 1e-5f);
  __hip_bfloat16* o = xw + (size_t)t * 384;
#pragma unroll
  for (int i = 0; i < 6; i++)
    o[ch[i]] = __float2bfloat16((v[i] - mean) * rstd * gw[ch[i]] + bw[ch[i]]);
}

// ---------- double LN (ln2 eps=1e-5, ffln eps=1e-6) on x_res -> yln bf16 ----------
__global__ __launch_bounds__(256)
void k_ln2ff(const float* __restrict__ xres, const float* __restrict__ g2,
             const float* __restrict__ b2, const float* __restrict__ gf,
             const float* __restrict__ bf_, __hip_bfloat16* __restrict__ yln) {
  int lane = threadIdx.x & 63;
  int t = blockIdx.x * 4 + (threadIdx.x >> 6);
  const float* xr = xres + (size_t)t * 384;
  float4 a  = *(const float4*)(xr + lane * 4);
  float2 c2 = *(const float2*)(xr + 256 + lane * 2);
  float v[6] = {a.x, a.y, a.z, a.w, c2.x, c2.y};
  int c0 = lane * 4, c1 = 256 + lane * 2;
  int ch[6] = {c0, c0 + 1, c0 + 2, c0 + 3, c1, c1 + 1};
  float s = 0.f, q = 0.f;
#pragma unroll
  for (int i = 0; i < 6; i++) { s += v[i]; q += v[i] * v[i]; }
#pragma unroll
  for (int m = 1; m < 64; m <<= 1) { s += __shfl_xor(s, m); q += __shfl_xor(q, m); }
  float mean = s * (1.f / 384.f);
  float rstd = rsqrtf(q * (1.f / 384.f) - mean * mean + 1e-5f);
  float y1[6];
  s = 0.f; q = 0.f;
#pragma unroll
  for (int i = 0; i < 6; i++) {
    y1[i] = (v[i] - mean) * rstd * g2[ch[i]] + b2[ch[i]];
    s += y1[i]; q += y1[i] * y1[i];
  }
#pragma unroll
  for (int m = 1; m < 64; m <<= 1) { s += __shfl_xor(s, m); q += __shfl_xor(q, m); }
  float m2 = s * (1.f / 384.f);
  float r2 = rsqrtf(q * (1.f / 384.f) - m2 * m2 + 1e-6f);
  __hip_bfloat16* o = yln + (size_t)t * 384;
#pragma unroll
  for (int i = 0; i < 6; i++)
    o[ch[i]] = __float2bfloat16((y1[i] - m2) * r2 * gf[ch[i]] + bf_[ch[i]]);
}

// ---------- 2-phase double-buffered bf16 MFMA GEMM ----------
// C(M,N) = A(M,K) @ Wt(N,K)^T + bias. 128x128 tile, BK=32,
// global_load_lds(16B) staging with next-tile prefetch in flight across MFMA,
// one barrier per K-step. 1D grid, bijective XCD swizzle, col-fastest.
enum { EPI_QKV = 0, EPI_PROJ = 1, EPI_FF1 = 2, EPI_FF2 = 3 };

template <int EPI>
__global__ __launch_bounds__(256)
void k_gemm(const __hip_bfloat16* __restrict__ A, const __hip_bfloat16* __restrict__ Wt,
            const float* __restrict__ bias, int K, int nCol, int cpx,
            const float* __restrict__ aux,        // PROJ: x; FF2: x_res
            float* __restrict__ out_f,            // PROJ: x_res; FF2: final out
            __hip_bfloat16* __restrict__ out_b) { // QKV: q base; FF1: hbuf
  __shared__ __hip_bfloat16 As[2][128 * 32];
  __shared__ __hip_bfloat16 Bs[2][128 * 32];
  int tid = threadIdx.x;
  int lane = tid & 63, wave = tid >> 6;
  int wr = wave >> 1, wc = wave & 1;
  int g = lane >> 4, r16 = lane & 15;

  int bid = blockIdx.x;
  int wg = (bid & 7) * cpx + (bid >> 3);
  int rB = wg / nCol;
  int rowBlk = rB * 128;
  int colBlk = (wg - rB * nCol) * 128;

  const __hip_bfloat16* Ab = A + (size_t)(rowBlk + (tid >> 2)) * K + (tid & 3) * 8;
  const __hip_bfloat16* Wb = Wt + (size_t)(colBlk + (tid >> 2)) * K + (tid & 3) * 8;
  size_t K64 = (size_t)K * 64;
  int wbase = wave * 512;  // wave-uniform LDS base (elements); HW adds lane*16B

  // prologue: stage tile 0 into buf 0
  gload_lds16(Ab,       &As[0][wbase]);
  gload_lds16(Ab + K64, &As[0][wbase + 2048]);
  gload_lds16(Wb,       &Bs[0][wbase]);
  gload_lds16(Wb + K64, &Bs[0][wbase + 2048]);
  __syncthreads();

  f32x4 acc[4][4] = {};
  int nt = K >> 5;
  int cur = 0;
  for (int t = 0; t < nt; ++t) {
    if (t + 1 < nt) {   // issue next tile's loads; they stay in flight across MFMA
      int k0 = (t + 1) << 5;
      int nb = cur ^ 1;
      gload_lds16(Ab + k0,       &As[nb][wbase]);
      gload_lds16(Ab + K64 + k0, &As[nb][wbase + 2048]);
      gload_lds16(Wb + k0,       &Bs[nb][wbase]);
      gload_lds16(Wb + K64 + k0, &Bs[nb][wbase + 2048]);
    }
    bf16x8 af[4], bfr[4];
#pragma unroll
    for (int mi = 0; mi < 4; mi++)
      af[mi] = *(const bf16x8*)(&As[cur][(wr * 64 + mi * 16 + r16) * 32 + g * 8]);
#pragma unroll
    for (int ni = 0; ni < 4; ni++)
      bfr[ni] = *(const bf16x8*)(&Bs[cur][(wc * 64 + ni * 16 + r16) * 32 + g * 8]);
#pragma unroll
    for (int mi = 0; mi < 4; mi++)
#pragma unroll
      for (int ni = 0; ni < 4; ni++)
        acc[mi][ni] = __builtin_amdgcn_mfma_f32_16x16x32_bf16(af[mi], bfr[ni], acc[mi][ni], 0, 0, 0);
    __syncthreads();   // drains next-tile vmcnt; protects buf reuse
    cur ^= 1;
  }

#pragma unroll
  for (int mi = 0; mi < 4; mi++) {
#pragma unroll
    for (int rr = 0; rr < 4; rr++) {
      int row = rowBlk + wr * 64 + mi * 16 + g * 4 + rr;
      int winr = 0, nn = 0; size_t nt2 = 0;
      if constexpr (EPI == EPI_QKV) { winr = row / 49; nn = row - winr * 49; }
      if constexpr (EPI == EPI_PROJ) { nt2 = win_to_nat(row); }
#pragma unroll
      for (int ni = 0; ni < 4; ni++) {
        int col = colBlk + wc * 64 + ni * 16 + r16;
        float val = acc[mi][ni][rr] + bias[col];
        if constexpr (EPI == EPI_QKV) {
          int which = col / 384; int rem = col - which * 384;
          int hh = rem >> 5, dd = rem & 31;
          size_t off = (((size_t)winr * 12 + hh) * 49 + nn) * 32 + dd;
          out_b[(size_t)which * 38535168u + off] = __float2bfloat16(val);
        } else if constexpr (EPI == EPI_PROJ) {
          out_f[nt2 * 384 + col] = val + aux[nt2 * 384 + col];
        } else if constexpr (EPI == EPI_FF1) {
          // tanh-form gelu (max |diff| vs erf-gelu ~1e-3, well under bf16 noise)
          float u = val * (val * val * 0.044715f + 1.0f) * 1.5957691216f; // 2*0.79788456
          float e = __expf(u);
          float th = 1.f - 2.f / (e + 1.f);   // tanh(u/2*2) safe at +-inf
          float ge = 0.5f * val * (1.f + th);
          out_b[(size_t)row * 1536 + col] = __float2bfloat16(ge);
        } else {
          out_f[(size_t)row * 384 + col] = val + aux[(size_t)row * 384 + col];
        }
      }
    }
  }
}

// ---------- windowed attention: 1 wave per (window, head) ----------
__global__ __launch_bounds__(256)
void k_attn(const __hip_bfloat16* __restrict__ q, const __hip_bfloat16* __restrict__ k,
            const __hip_bfloat16* __restrict__ v, const float* __restrict__ rpb,
            __hip_bfloat16* __restrict__ o) {
  __shared__ __hip_bfloat16 P[4][64][72];
  int tid = threadIdx.x;
  int lane = tid & 63, wave = tid >> 6;
  int g = lane >> 4, r16 = lane & 15;
  int gid = blockIdx.x * 4 + wave;              // 0..24575 window-heads
  int wi = gid / 12, h = gid - (gid / 12) * 12;
  int wimg = wi & 63;
  int hb = wimg >> 3, wb = wimg & 7;
  size_t base = ((size_t)wi * 12 + h) * (49 * 32);
  const __hip_bfloat16* qb = q + base;
  const __hip_bfloat16* kb = k + base;
  const __hip_bfloat16* vb = v + base;

  bf16x8 zf = {0, 0, 0, 0, 0, 0, 0, 0};
  bf16x8 qf[4], kf[4];
#pragma unroll
  for (int mi = 0; mi < 4; mi++) {
    int row = mi * 16 + r16;
    qf[mi] = (row < 49) ? *(const bf16x8*)(qb + row * 32 + g * 8) : zf;
    kf[mi] = (row < 49) ? *(const bf16x8*)(kb + row * 32 + g * 8) : zf;
  }
  f32x4 fz = {0.f, 0.f, 0.f, 0.f};
  f32x4 S[4][4];
#pragma unroll
  for (int mi = 0; mi < 4; mi++)
#pragma unroll
    for (int ni = 0; ni < 4; ni++)
      S[mi][ni] = __builtin_amdgcn_mfma_f32_16x16x32_bf16(qf[mi], kf[ni], fz, 0, 0, 0);

  int kiA[4], kjA[4], rkA[4], cvA[4];
#pragma unroll
  for (int ni = 0; ni < 4; ni++) {
    int col = ni * 16 + r16;
    cvA[ni] = (col < 49);
    int ki = col / 7, kj = col - (col / 7) * 7;
    kiA[ni] = ki; kjA[ni] = kj;
    int hg = hb * 7 + ki, wg = wb * 7 + kj;
    int rh = (hg < 49) ? 0 : ((hg < 53) ? 1 : 2);
    int rw = (wg < 49) ? 0 : ((wg < 53) ? 1 : 2);
    rkA[ni] = rh * 3 + rw;
  }

#pragma unroll
  for (int mi = 0; mi < 4; mi++) {
#pragma unroll
    for (int rr = 0; rr < 4; rr++) {
      int row = mi * 16 + g * 4 + rr;
      float sv[4];
      float mx = -1e30f;
      int qi = row / 7, qj = row - (row / 7) * 7;
      int hgq = hb * 7 + qi, wgq = wb * 7 + qj;
      int rhq = (hgq < 49) ? 0 : ((hgq < 53) ? 1 : 2);
      int rwq = (wgq < 49) ? 0 : ((wgq < 53) ? 1 : 2);
      int rq = rhq * 3 + rwq;
#pragma unroll
      for (int ni = 0; ni < 4; ni++) {
        float s = -1e30f;
        if (row < 49 && cvA[ni]) {
          int idx = (qi - kiA[ni] + 6) * 13 + (qj - kjA[ni] + 6);
          float maskv = (rq != rkA[ni]) ? -100.f : 0.f;
          s = S[mi][ni][rr] * SCALE + rpb[idx * 12 + h] + maskv;
        }
        sv[ni] = s;
        mx = fmaxf(mx, s);
      }
#pragma unroll
      for (int m = 1; m <= 8; m <<= 1) mx = fmaxf(mx, __shfl_xor(mx, m));
      float sum = 0.f;
#pragma unroll
      for (int ni = 0; ni < 4; ni++) {
        float p = __expf(sv[ni] - mx);
        sv[ni] = p; sum += p;
      }
#pragma unroll
      for (int m = 1; m <= 8; m <<= 1) sum += __shfl_xor(sum, m);
      float inv = 1.f / sum;
#pragma unroll
      for (int ni = 0; ni < 4; ni++)
        P[wave][row][ni * 16 + r16] = __float2bfloat16(sv[ni] * inv);
    }
  }

  f32x4 O[4][2] = {};
#pragma unroll
  for (int ks = 0; ks < 2; ks++) {
    bf16x8 pf[4];
#pragma unroll
    for (int mi = 0; mi < 4; mi++)
      pf[mi] = *(const bf16x8*)(&P[wave][mi * 16 + r16][ks * 32 + g * 8]);
#pragma unroll
    for (int ni = 0; ni < 2; ni++) {
      bf16x8 vf = zf;
#pragma unroll
      for (int j = 0; j < 8; j++) {
        int m = ks * 32 + g * 8 + j;
        if (m < 49) vf[j] = ((const short*)vb)[m * 32 + ni * 16 + r16];
      }
#pragma unroll
      for (int mi = 0; mi < 4; mi++)
        O[mi][ni] = __builtin_amdgcn_mfma_f32_16x16x32_bf16(pf[mi], vf, O[mi][ni], 0, 0, 0);
    }
  }

#pragma unroll
  for (int mi = 0; mi < 4; mi++)
#pragma unroll
    for (int rr = 0; rr < 4; rr++) {
      int row = mi * 16 + g * 4 + rr;
      if (row < 49) {
#pragma unroll
        for (int ni = 0; ni < 2; ni++) {
          int col = ni * 16 + r16;
          o[(((size_t)wi * 49 + row) * 12 + h) * 32 + col] = __float2bfloat16(O[mi][ni][rr]);
        }
      }
    }
}

// ---------- host launch ----------
extern "C" void kernel_launch(void* const* d_in, const int* in_sizes, int n_in,
                              void* d_out, int out_size, void* d_ws, size_t ws_size,
                              hipStream_t stream) {
  const float* x      = (const float*)d_in[0];
  const float* ln1_g  = (const float*)d_in[1];
  const float* ln1_b  = (const float*)d_in[2];
  const float* qkv_w  = (const float*)d_in[3];
  const float* qkv_b  = (const float*)d_in[4];
  const float* proj_w = (const float*)d_in[5];
  const float* proj_b = (const float*)d_in[6];
  const float* rpb    = (const float*)d_in[7];
  const float* ln2_g  = (const float*)d_in[8];
  const float* ln2_b  = (const float*)d_in[9];
  const float* ffg    = (const float*)d_in[10];
  const float* ffb    = (const float*)d_in[11];
  const float* ff1_w  = (const float*)d_in[12];
  const float* ff1_b  = (const float*)d_in[13];
  const float* ff2_w  = (const float*)d_in[14];
  const float* ff2_b  = (const float*)d_in[15];
  float* out = (float*)d_out;

  char* ws = (char*)d_ws;
  // layout: [xw 77MB | q 77MB | k 77MB | v 77MB | x_res 154MB | yln 77MB | weights]
  // hbuf (308MB) aliases [xw|q|k|v] (dead by FF1); attn_out aliases xw (dead after QKV)
  __hip_bfloat16* xw     = (__hip_bfloat16*)ws;
  __hip_bfloat16* qbuf   = (__hip_bfloat16*)(ws + 77070336u);
  __hip_bfloat16* kbuf   = qbuf + 38535168u;
  __hip_bfloat16* vbuf   = kbuf + 38535168u;
  __hip_bfloat16* attn_o = xw;
  __hip_bfloat16* hbuf   = (__hip_bfloat16*)ws;
  float*          x_res  = (float*)(ws + 308281344u);
  __hip_bfloat16* yln    = (__hip_bfloat16*)(ws + 462422016u);
  __hip_bfloat16* qkv_wt = (__hip_bfloat16*)(ws + 539492352u);
  __hip_bfloat16* proj_wt = qkv_wt + 442368u;
  __hip_bfloat16* ff1_wt  = proj_wt + 147456u;
  __hip_bfloat16* ff2_wt  = ff1_wt + 589824u;

  // weight prep (tiled transpose: K/32 x N/32 tiles)
  k_transpose<<<dim3(1152 / 32, 384 / 32), dim3(256), 0, stream>>>(qkv_w, qkv_wt, 384, 1152);
  k_transpose<<<dim3(384 / 32, 384 / 32), dim3(256), 0, stream>>>(proj_w, proj_wt, 384, 384);
  k_transpose<<<dim3(1536 / 32, 384 / 32), dim3(256), 0, stream>>>(ff1_w, ff1_wt, 384, 1536);
  k_transpose<<<dim3(384 / 32, 1536 / 32), dim3(256), 0, stream>>>(ff2_w, ff2_wt, 1536, 384);

  // LN1 + shift + window partition
  k_ln1<<<dim3(25088), dim3(256), 0, stream>>>(x, ln1_g, ln1_b, xw);

  // QKV GEMM: M=100352, N=1152, K=384 -> nwg = 784*9 = 7056
  k_gemm<EPI_QKV><<<dim3(7056), dim3(256), 0, stream>>>(xw, qkv_wt, qkv_b, 384, 9, 7056 / 8,
                                                        nullptr, nullptr, qbuf);
  // attention: 24576 window-heads, 4 per block
  k_attn<<<dim3(6144), dim3(256), 0, stream>>>(qbuf, kbuf, vbuf, rpb, attn_o);
  // proj GEMM + window reverse + residual -> x_res: nwg = 2352
  k_gemm<EPI_PROJ><<<dim3(2352), dim3(256), 0, stream>>>(attn_o, proj_wt, proj_b, 384, 3, 2352 / 8,
                                                         x, x_res, nullptr);
  // LN2 + ffLN
  k_ln2ff<<<dim3(25088), dim3(256), 0, stream>>>(x_res, ln2_g, ln2_b, ffg, ffb, yln);
  // FF1 + gelu: nwg = 9408
  k_gemm<EPI_FF1><<<dim3(9408), dim3(256), 0, stream>>>(yln, ff1_wt, ff1_b, 384, 12, 9408 / 8,
                                                        nullptr, nullptr, hbuf);
  // FF2 + residual -> out: K=1536, nwg = 2352
  k_gemm<EPI_FF2><<<dim3(2352), dim3(256), 0, stream>>>(hbuf, ff2_wt, ff2_b, 1536, 3, 2352 / 8,
                                                        x_res, out, nullptr);
}

// Round 4
// 1061.829 us; speedup vs baseline: 1.1267x; 1.0040x over previous
//
#include <hip/hip_runtime.h>
#include <hip/hip_bf16.h>

typedef short bf16x8 __attribute__((ext_vector_type(8)));
typedef float f32x4  __attribute__((ext_vector_type(4)));

// ---------- problem constants ----------
// B=32, H=W=56, C=384, NH=12, WS=7, SS=3, DH=32, N=49, HID=1536
static constexpr float SCALE = 0.17677669529663687f; // 32^-0.5

__device__ __forceinline__ void gload_lds16(const void* g, void* l) {
  __builtin_amdgcn_global_load_lds(
      (const __attribute__((address_space(1))) unsigned int*)g,
      (__attribute__((address_space(3))) unsigned int*)l, 16, 0, 0);
}

// map windowed-layout token t -> natural token index (b*3136 + h*56 + w)
__device__ __forceinline__ size_t win_to_nat(int t) {
  int win = t / 49; int n = t - win * 49;
  int bb = win >> 6; int wimg = win & 63;
  int hb = wimg >> 3, wb = wimg & 7;
  int nr = n / 7, nc = n - nr * 7;
  int hh = hb * 7 + nr + 3; if (hh >= 56) hh -= 56;
  int ww = wb * 7 + nc + 3; if (ww >= 56) ww -= 56;
  return (size_t)bb * 3136 + (size_t)hh * 56 + ww;
}

// ---------- LDS-tiled weight transpose+cast: W (K x N f32) -> Wt (N x K bf16) ----
__global__ __launch_bounds__(256)
void k_transpose(const float* __restrict__ W, __hip_bfloat16* __restrict__ Wt,
                 int K, int N) {
  __shared__ float tile[32][33];
  int tx = threadIdx.x & 31, ty = threadIdx.x >> 5;  // 32 x 8
  int tc = blockIdx.x, tr = blockIdx.y;              // col-tile (N), row-tile (K)
#pragma unroll
  for (int r = 0; r < 32; r += 8)
    tile[r + ty][tx] = W[(size_t)(tr * 32 + r + ty) * N + tc * 32 + tx];
  __syncthreads();
#pragma unroll
  for (int r = 0; r < 32; r += 8)
    Wt[(size_t)(tc * 32 + r + ty) * K + tr * 32 + tx] =
        __float2bfloat16(tile[tx][r + ty]);
}

// ---------- LN1 + roll(-3,-3) + window partition; out bf16 windowed layout ----------
__global__ __launch_bounds__(256)
void k_ln1(const float* __restrict__ x, const float* __restrict__ gw,
           const float* __restrict__ bw, __hip_bfloat16* __restrict__ xw) {
  int lane = threadIdx.x & 63;
  int t = blockIdx.x * 4 + (threadIdx.x >> 6);
  size_t nt = win_to_nat(t);
  const float* xr = x + nt * 384;
  float4 a  = *(const float4*)(xr + lane * 4);
  float2 c2 = *(const float2*)(xr + 256 + lane * 2);
  float v[6] = {a.x, a.y, a.z, a.w, c2.x, c2.y};
  int c0 = lane * 4, c1 = 256 + lane * 2;
  int ch[6] = {c0, c0 + 1, c0 + 2, c0 + 3, c1, c1 + 1};
  float s = 0.f, q = 0.f;
#pragma unroll
  for (int i = 0; i < 6; i++) { s += v[i]; q += v[i] * v[i]; }
#pragma unroll
  for (int m = 1; m < 64; m <<= 1) { s += __shfl_xor(s, m); q += __shfl_xor(q, m); }
  float mean = s * (1.f / 384.f);
  float rstd = rsqrtf(q * (1.f / 384.f) - mean * mean + 1e-5f);
  __hip_bfloat16* o = xw + (size_t)t * 384;
#pragma unroll
  for (int i = 0; i < 6; i++)
    o[ch[i]] = __float2bfloat16((v[i] - mean) * rstd * gw[ch[i]] + bw[ch[i]]);
}

// ---------- double LN (ln2 eps=1e-5, ffln eps=1e-6) on x_res -> yln bf16 ----------
__global__ __launch_bounds__(256)
void k_ln2ff(const float* __restrict__ xres, const float* __restrict__ g2,
             const float* __restrict__ b2, const float* __restrict__ gf,
             const float* __restrict__ bf_, __hip_bfloat16* __restrict__ yln) {
  int lane = threadIdx.x & 63;
  int t = blockIdx.x * 4 + (threadIdx.x >> 6);
  const float* xr = xres + (size_t)t * 384;
  float4 a  = *(const float4*)(xr + lane * 4);
  float2 c2 = *(const float2*)(xr + 256 + lane * 2);
  float v[6] = {a.x, a.y, a.z, a.w, c2.x, c2.y};
  int c0 = lane * 4, c1 = 256 + lane * 2;
  int ch[6] = {c0, c0 + 1, c0 + 2, c0 + 3, c1, c1 + 1};
  float s = 0.f, q = 0.f;
#pragma unroll
  for (int i = 0; i < 6; i++) { s += v[i]; q += v[i] * v[i]; }
#pragma unroll
  for (int m = 1; m < 64; m <<= 1) { s += __shfl_xor(s, m); q += __shfl_xor(q, m); }
  float mean = s * (1.f / 384.f);
  float rstd = rsqrtf(q * (1.f / 384.f) - mean * mean + 1e-5f);
  float y1[6];
  s = 0.f; q = 0.f;
#pragma unroll
  for (int i = 0; i < 6; i++) {
    y1[i] = (v[i] - mean) * rstd * g2[ch[i]] + b2[ch[i]];
    s += y1[i]; q += y1[i] * y1[i];
  }
#pragma unroll
  for (int m = 1; m < 64; m <<= 1) { s += __shfl_xor(s, m); q += __shfl_xor(q, m); }
  float m2 = s * (1.f / 384.f);
  float r2 = rsqrtf(q * (1.f / 384.f) - m2 * m2 + 1e-6f);
  __hip_bfloat16* o = yln + (size_t)t * 384;
#pragma unroll
  for (int i = 0; i < 6; i++)
    o[ch[i]] = __float2bfloat16((y1[i] - m2) * r2 * gf[ch[i]] + bf_[ch[i]]);
}

// ---------- depth-2 counted-vmcnt bf16 MFMA GEMM ----------
// C(M,N) = A(M,K) @ Wt(N,K)^T + bias. 128x128 tile, BK=32, 3 LDS buffers,
// tiles t+1,t+2 in flight across raw barriers (vmcnt(8) steady state),
// T2 both-sides XOR swizzle (global-source pre-swizzle + swizzled ds_read),
// T5 setprio around MFMA cluster. K must be a multiple of 96 (nt % 3 == 0).
enum { EPI_QKV = 0, EPI_PROJ = 1, EPI_FF1 = 2, EPI_FF2 = 3 };

template <int EPI>
__global__ __launch_bounds__(256)
void k_gemm(const __hip_bfloat16* __restrict__ A, const __hip_bfloat16* __restrict__ Wt,
            const float* __restrict__ bias, int K, int nCol, int cpx,
            const float* __restrict__ aux,        // PROJ: x; FF2: x_res
            float* __restrict__ out_f,            // PROJ: x_res; FF2: final out
            __hip_bfloat16* __restrict__ out_b) { // QKV: q base; FF1: hbuf
  __shared__ __hip_bfloat16 As[3][4096];
  __shared__ __hip_bfloat16 Bs[3][4096];
  int tid = threadIdx.x;
  int lane = tid & 63, wave = tid >> 6;
  int wr = wave >> 1, wc = wave & 1;
  int g = lane >> 4, r16 = lane & 15;

  int bid = blockIdx.x;
  int wg = (bid & 7) * cpx + (bid >> 3);
  int rB = wg / nCol;
  int rowBlk = rB * 128;
  int colBlk = (wg - rB * nCol) * 128;

  // staging: thread t -> row (tid>>2), source column chunk XOR-swizzled by row&3
  int srow = tid >> 2;
  int sco  = (tid & 3) ^ (srow & 3);
  const __hip_bfloat16* Ab = A + (size_t)(rowBlk + srow) * K + sco * 8;
  const __hip_bfloat16* Wb = Wt + (size_t)(colBlk + srow) * K + sco * 8;
  size_t K64 = (size_t)K * 64;
  int wbase = wave * 512;  // wave-uniform LDS base (elements); HW adds lane*16B

  // read offsets: slot s of row holds global chunk s^(row&3); row%4 == r16%4
  int gs = g ^ (r16 & 3);
  int aoff = wr * 2048 + r16 * 32 + gs * 8;
  int boff = wc * 2048 + r16 * 32 + gs * 8;

#define STAGE(SB, T)                                          \
  {                                                           \
    int k0s = (T) << 5;                                       \
    gload_lds16(Ab + k0s,       &As[SB][wbase]);              \
    gload_lds16(Ab + K64 + k0s, &As[SB][wbase + 2048]);       \
    gload_lds16(Wb + k0s,       &Bs[SB][wbase]);              \
    gload_lds16(Wb + K64 + k0s, &Bs[SB][wbase + 2048]);       \
  }

  f32x4 acc[4][4] = {};
  int ntiles = K >> 5;

  // prologue: tiles 0,1 in flight
  STAGE(0, 0)
  STAGE(1, 1)

#define GSTEP(CB, SB, T)                                                     \
  {                                                                          \
    if ((T) + 2 < ntiles) {                                                  \
      STAGE(SB, (T) + 2)                                                     \
      asm volatile("s_waitcnt vmcnt(8)" ::: "memory");                       \
    } else if ((T) + 1 < ntiles) {                                           \
      asm volatile("s_waitcnt vmcnt(4)" ::: "memory");                       \
    } else {                                                                 \
      asm volatile("s_waitcnt vmcnt(0)" ::: "memory");                       \
    }                                                                        \
    __builtin_amdgcn_s_barrier();                                            \
    asm volatile("" ::: "memory");                                           \
    bf16x8 af[4], bfr[4];                                                    \
    _Pragma("unroll") for (int mi = 0; mi < 4; mi++)                         \
        af[mi] = *(const bf16x8*)(&As[CB][aoff + mi * 512]);                 \
    _Pragma("unroll") for (int ni = 0; ni < 4; ni++)                         \
        bfr[ni] = *(const bf16x8*)(&Bs[CB][boff + ni * 512]);                \
    __builtin_amdgcn_s_setprio(1);                                           \
    _Pragma("unroll") for (int mi = 0; mi < 4; mi++)                         \
        _Pragma("unroll") for (int ni = 0; ni < 4; ni++)                     \
            acc[mi][ni] = __builtin_amdgcn_mfma_f32_16x16x32_bf16(           \
                af[mi], bfr[ni], acc[mi][ni], 0, 0, 0);                      \
    __builtin_amdgcn_s_setprio(0);                                           \
    asm volatile("" ::: "memory");                                           \
    __builtin_amdgcn_s_barrier();                                            \
  }

  for (int t = 0; t < ntiles; t += 3) {
    GSTEP(0, 2, t)
    GSTEP(1, 0, t + 1)
    GSTEP(2, 1, t + 2)
  }
#undef GSTEP
#undef STAGE

#pragma unroll
  for (int mi = 0; mi < 4; mi++) {
#pragma unroll
    for (int rr = 0; rr < 4; rr++) {
      int row = rowBlk + wr * 64 + mi * 16 + g * 4 + rr;
      int winr = 0, nn = 0; size_t nt2 = 0;
      if constexpr (EPI == EPI_QKV) { winr = row / 49; nn = row - winr * 49; }
      if constexpr (EPI == EPI_PROJ) { nt2 = win_to_nat(row); }
#pragma unroll
      for (int ni = 0; ni < 4; ni++) {
        int col = colBlk + wc * 64 + ni * 16 + r16;
        float val = acc[mi][ni][rr] + bias[col];
        if constexpr (EPI == EPI_QKV) {
          int which = col / 384; int rem = col - which * 384;
          int hh = rem >> 5, dd = rem & 31;
          size_t off = (((size_t)winr * 12 + hh) * 49 + nn) * 32 + dd;
          out_b[(size_t)which * 38535168u + off] = __float2bfloat16(val);
        } else if constexpr (EPI == EPI_PROJ) {
          out_f[nt2 * 384 + col] = val + aux[nt2 * 384 + col];
        } else if constexpr (EPI == EPI_FF1) {
          // tanh-form gelu (max |diff| vs erf-gelu ~1e-3)
          float u = val * (val * val * 0.044715f + 1.0f) * 1.5957691216f;
          float e = __expf(u);
          float th = 1.f - 2.f / (e + 1.f);
          float ge = 0.5f * val * (1.f + th);
          out_b[(size_t)row * 1536 + col] = __float2bfloat16(ge);
        } else {
          out_f[(size_t)row * 384 + col] = val + aux[(size_t)row * 384 + col];
        }
      }
    }
  }
}

// ---------- windowed attention: 1 wave per (window, head) ----------
__global__ __launch_bounds__(256)
void k_attn(const __hip_bfloat16* __restrict__ q, const __hip_bfloat16* __restrict__ k,
            const __hip_bfloat16* __restrict__ v, const float* __restrict__ rpb,
            __hip_bfloat16* __restrict__ o) {
  __shared__ __hip_bfloat16 P[4][64][72];
  int tid = threadIdx.x;
  int lane = tid & 63, wave = tid >> 6;
  int g = lane >> 4, r16 = lane & 15;
  int gid = blockIdx.x * 4 + wave;              // 0..24575 window-heads
  int wi = gid / 12, h = gid - (gid / 12) * 12;
  int wimg = wi & 63;
  int hb = wimg >> 3, wb = wimg & 7;
  size_t base = ((size_t)wi * 12 + h) * (49 * 32);
  const __hip_bfloat16* qb = q + base;
  const __hip_bfloat16* kb = k + base;
  const __hip_bfloat16* vb = v + base;

  bf16x8 zf = {0, 0, 0, 0, 0, 0, 0, 0};
  bf16x8 qf[4], kf[4];
#pragma unroll
  for (int mi = 0; mi < 4; mi++) {
    int row = mi * 16 + r16;
    qf[mi] = (row < 49) ? *(const bf16x8*)(qb + row * 32 + g * 8) : zf;
    kf[mi] = (row < 49) ? *(const bf16x8*)(kb + row * 32 + g * 8) : zf;
  }
  f32x4 fz = {0.f, 0.f, 0.f, 0.f};
  f32x4 S[4][4];
#pragma unroll
  for (int mi = 0; mi < 4; mi++)
#pragma unroll
    for (int ni = 0; ni < 4; ni++)
      S[mi][ni] = __builtin_amdgcn_mfma_f32_16x16x32_bf16(qf[mi], kf[ni], fz, 0, 0, 0);

  int kiA[4], kjA[4], rkA[4], cvA[4];
#pragma unroll
  for (int ni = 0; ni < 4; ni++) {
    int col = ni * 16 + r16;
    cvA[ni] = (col < 49);
    int ki = col / 7, kj = col - (col / 7) * 7;
    kiA[ni] = ki; kjA[ni] = kj;
    int hg = hb * 7 + ki, wg = wb * 7 + kj;
    int rh = (hg < 49) ? 0 : ((hg < 53) ? 1 : 2);
    int rw = (wg < 49) ? 0 : ((wg < 53) ? 1 : 2);
    rkA[ni] = rh * 3 + rw;
  }

#pragma unroll
  for (int mi = 0; mi < 4; mi++) {
#pragma unroll
    for (int rr = 0; rr < 4; rr++) {
      int row = mi * 16 + g * 4 + rr;
      float sv[4];
      float mx = -1e30f;
      int qi = row / 7, qj = row - (row / 7) * 7;
      int hgq = hb * 7 + qi, wgq = wb * 7 + qj;
      int rhq = (hgq < 49) ? 0 : ((hgq < 53) ? 1 : 2);
      int rwq = (wgq < 49) ? 0 : ((wgq < 53) ? 1 : 2);
      int rq = rhq * 3 + rwq;
#pragma unroll
      for (int ni = 0; ni < 4; ni++) {
        float s = -1e30f;
        if (row < 49 && cvA[ni]) {
          int idx = (qi - kiA[ni] + 6) * 13 + (qj - kjA[ni] + 6);
          float maskv = (rq != rkA[ni]) ? -100.f : 0.f;
          s = S[mi][ni][rr] * SCALE + rpb[idx * 12 + h] + maskv;
        }
        sv[ni] = s;
        mx = fmaxf(mx, s);
      }
#pragma unroll
      for (int m = 1; m <= 8; m <<= 1) mx = fmaxf(mx, __shfl_xor(mx, m));
      float sum = 0.f;
#pragma unroll
      for (int ni = 0; ni < 4; ni++) {
        float p = __expf(sv[ni] - mx);
        sv[ni] = p; sum += p;
      }
#pragma unroll
      for (int m = 1; m <= 8; m <<= 1) sum += __shfl_xor(sum, m);
      float inv = 1.f / sum;
#pragma unroll
      for (int ni = 0; ni < 4; ni++)
        P[wave][row][ni * 16 + r16] = __float2bfloat16(sv[ni] * inv);
    }
  }

  f32x4 O[4][2] = {};
#pragma unroll
  for (int ks = 0; ks < 2; ks++) {
    bf16x8 pf[4];
#pragma unroll
    for (int mi = 0; mi < 4; mi++)
      pf[mi] = *(const bf16x8*)(&P[wave][mi * 16 + r16][ks * 32 + g * 8]);
#pragma unroll
    for (int ni = 0; ni < 2; ni++) {
      bf16x8 vf = zf;
#pragma unroll
      for (int j = 0; j < 8; j++) {
        int m = ks * 32 + g * 8 + j;
        if (m < 49) vf[j] = ((const short*)vb)[m * 32 + ni * 16 + r16];
      }
#pragma unroll
      for (int mi = 0; mi < 4; mi++)
        O[mi][ni] = __builtin_amdgcn_mfma_f32_16x16x32_bf16(pf[mi], vf, O[mi][ni], 0, 0, 0);
    }
  }

#pragma unroll
  for (int mi = 0; mi < 4; mi++)
#pragma unroll
    for (int rr = 0; rr < 4; rr++) {
      int row = mi * 16 + g * 4 + rr;
      if (row < 49) {
#pragma unroll
        for (int ni = 0; ni < 2; ni++) {
          int col = ni * 16 + r16;
          o[(((size_t)wi * 49 + row) * 12 + h) * 32 + col] = __float2bfloat16(O[mi][ni][rr]);
        }
      }
    }
}

// ---------- host launch ----------
extern "C" void kernel_launch(void* const* d_in, const int* in_sizes, int n_in,
                              void* d_out, int out_size, void* d_ws, size_t ws_size,
                              hipStream_t stream) {
  const float* x      = (const float*)d_in[0];
  const float* ln1_g  = (const float*)d_in[1];
  const float* ln1_b  = (const float*)d_in[2];
  const float* qkv_w  = (const float*)d_in[3];
  const float* qkv_b  = (const float*)d_in[4];
  const float* proj_w = (const float*)d_in[5];
  const float* proj_b = (const float*)d_in[6];
  const float* rpb    = (const float*)d_in[7];
  const float* ln2_g  = (const float*)d_in[8];
  const float* ln2_b  = (const float*)d_in[9];
  const float* ffg    = (const float*)d_in[10];
  const float* ffb    = (const float*)d_in[11];
  const float* ff1_w  = (const float*)d_in[12];
  const float* ff1_b  = (const float*)d_in[13];
  const float* ff2_w  = (const float*)d_in[14];
  const float* ff2_b  = (const float*)d_in[15];
  float* out = (float*)d_out;

  char* ws = (char*)d_ws;
  __hip_bfloat16* xw     = (__hip_bfloat16*)ws;
  __hip_bfloat16* qbuf   = (__hip_bfloat16*)(ws + 77070336u);
  __hip_bfloat16* kbuf   = qbuf + 38535168u;
  __hip_bfloat16* vbuf   = kbuf + 38535168u;
  __hip_bfloat16* attn_o = xw;
  __hip_bfloat16* hbuf   = (__hip_bfloat16*)ws;
  float*          x_res  = (float*)(ws + 308281344u);
  __hip_bfloat16* yln    = (__hip_bfloat16*)(ws + 462422016u);
  __hip_bfloat16* qkv_wt = (__hip_bfloat16*)(ws + 539492352u);
  __hip_bfloat16* proj_wt = qkv_wt + 442368u;
  __hip_bfloat16* ff1_wt  = proj_wt + 147456u;
  __hip_bfloat16* ff2_wt  = ff1_wt + 589824u;

  // weight prep (tiled transpose: K/32 x N/32 tiles)
  k_transpose<<<dim3(1152 / 32, 384 / 32), dim3(256), 0, stream>>>(qkv_w, qkv_wt, 384, 1152);
  k_transpose<<<dim3(384 / 32, 384 / 32), dim3(256), 0, stream>>>(proj_w, proj_wt, 384, 384);
  k_transpose<<<dim3(1536 / 32, 384 / 32), dim3(256), 0, stream>>>(ff1_w, ff1_wt, 384, 1536);
  k_transpose<<<dim3(384 / 32, 1536 / 32), dim3(256), 0, stream>>>(ff2_w, ff2_wt, 1536, 384);

  // LN1 + shift + window partition
  k_ln1<<<dim3(25088), dim3(256), 0, stream>>>(x, ln1_g, ln1_b, xw);

  // QKV GEMM: M=100352, N=1152, K=384 -> nwg = 784*9 = 7056
  k_gemm<EPI_QKV><<<dim3(7056), dim3(256), 0, stream>>>(xw, qkv_wt, qkv_b, 384, 9, 7056 / 8,
                                                        nullptr, nullptr, qbuf);
  // attention: 24576 window-heads, 4 per block
  k_attn<<<dim3(6144), dim3(256), 0, stream>>>(qbuf, kbuf, vbuf, rpb, attn_o);
  // proj GEMM + window reverse + residual -> x_res: nwg = 2352
  k_gemm<EPI_PROJ><<<dim3(2352), dim3(256), 0, stream>>>(attn_o, proj_wt, proj_b, 384, 3, 2352 / 8,
                                                         x, x_res, nullptr);
  // LN2 + ffLN
  k_ln2ff<<<dim3(25088), dim3(256), 0, stream>>>(x_res, ln2_g, ln2_b, ffg, ffb, yln);
  // FF1 + gelu: nwg = 9408
  k_gemm<EPI_FF1><<<dim3(9408), dim3(256), 0, stream>>>(yln, ff1_wt, ff1_b, 384, 12, 9408 / 8,
                                                        nullptr, nullptr, hbuf);
  // FF2 + residual -> out: K=1536, nwg = 2352
  k_gemm<EPI_FF2><<<dim3(2352), dim3(256), 0, stream>>>(hbuf, ff2_wt, ff2_b, 1536, 3, 2352 / 8,
                                                        x_res, out, nullptr);
}

// Round 6
// 949.605 us; speedup vs baseline: 1.2598x; 1.1182x over previous
//
#include <hip/hip_runtime.h>
#include <hip/hip_bf16.h>

typedef short bf16x8 __attribute__((ext_vector_type(8)));
typedef float f32x4  __attribute__((ext_vector_type(4)));

// ---------- problem constants ----------
// B=32, H=W=56, C=384, NH=12, WS=7, SS=3, DH=32, N=49, HID=1536
static constexpr float SCALE = 0.17677669529663687f; // 32^-0.5

__device__ __forceinline__ void gload_lds16(const void* g, void* l) {
  __builtin_amdgcn_global_load_lds(
      (const __attribute__((address_space(1))) unsigned int*)g,
      (__attribute__((address_space(3))) unsigned int*)l, 16, 0, 0);
}

// map windowed-layout token t -> natural token index (b*3136 + h*56 + w)
__device__ __forceinline__ size_t win_to_nat(int t) {
  int win = t / 49; int n = t - win * 49;
  int bb = win >> 6; int wimg = win & 63;
  int hb = wimg >> 3, wb = wimg & 7;
  int nr = n / 7, nc = n - nr * 7;
  int hh = hb * 7 + nr + 3; if (hh >= 56) hh -= 56;
  int ww = wb * 7 + nc + 3; if (ww >= 56) ww -= 56;
  return (size_t)bb * 3136 + (size_t)hh * 56 + ww;
}

// ---------- LDS-tiled weight transpose+cast: W (K x N f32) -> Wt (N x K bf16) ----
__global__ __launch_bounds__(256)
void k_transpose(const float* __restrict__ W, __hip_bfloat16* __restrict__ Wt,
                 int K, int N) {
  __shared__ float tile[32][33];
  int tx = threadIdx.x & 31, ty = threadIdx.x >> 5;  // 32 x 8
  int tc = blockIdx.x, tr = blockIdx.y;              // col-tile (N), row-tile (K)
#pragma unroll
  for (int r = 0; r < 32; r += 8)
    tile[r + ty][tx] = W[(size_t)(tr * 32 + r + ty) * N + tc * 32 + tx];
  __syncthreads();
#pragma unroll
  for (int r = 0; r < 32; r += 8)
    Wt[(size_t)(tc * 32 + r + ty) * K + tr * 32 + tx] =
        __float2bfloat16(tile[tx][r + ty]);
}

// ---------- LN1 + roll(-3,-3) + window partition; out bf16 windowed layout ----------
__global__ __launch_bounds__(256)
void k_ln1(const float* __restrict__ x, const float* __restrict__ gw,
           const float* __restrict__ bw, __hip_bfloat16* __restrict__ xw) {
  int lane = threadIdx.x & 63;
  int t = blockIdx.x * 4 + (threadIdx.x >> 6);
  size_t nt = win_to_nat(t);
  const float* xr = x + nt * 384;
  float4 a  = *(const float4*)(xr + lane * 4);
  float2 c2 = *(const float2*)(xr + 256 + lane * 2);
  float v[6] = {a.x, a.y, a.z, a.w, c2.x, c2.y};
  int c0 = lane * 4, c1 = 256 + lane * 2;
  int ch[6] = {c0, c0 + 1, c0 + 2, c0 + 3, c1, c1 + 1};
  float s = 0.f, q = 0.f;
#pragma unroll
  for (int i = 0; i < 6; i++) { s += v[i]; q += v[i] * v[i]; }
#pragma unroll
  for (int m = 1; m < 64; m <<= 1) { s += __shfl_xor(s, m); q += __shfl_xor(q, m); }
  float mean = s * (1.f / 384.f);
  float rstd = rsqrtf(q * (1.f / 384.f) - mean * mean + 1e-5f);
  __hip_bfloat16* o = xw + (size_t)t * 384;
#pragma unroll
  for (int i = 0; i < 6; i++)
    o[ch[i]] = __float2bfloat16((v[i] - mean) * rstd * gw[ch[i]] + bw[ch[i]]);
}

// ---------- double LN (ln2 eps=1e-5, ffln eps=1e-6) on x_res -> yln bf16 ----------
__global__ __launch_bounds__(256)
void k_ln2ff(const float* __restrict__ xres, const float* __restrict__ g2,
             const float* __restrict__ b2, const float* __restrict__ gf,
             const float* __restrict__ bf_, __hip_bfloat16* __restrict__ yln) {
  int lane = threadIdx.x & 63;
  int t = blockIdx.x * 4 + (threadIdx.x >> 6);
  const float* xr = xres + (size_t)t * 384;
  float4 a  = *(const float4*)(xr + lane * 4);
  float2 c2 = *(const float2*)(xr + 256 + lane * 2);
  float v[6] = {a.x, a.y, a.z, a.w, c2.x, c2.y};
  int c0 = lane * 4, c1 = 256 + lane * 2;
  int ch[6] = {c0, c0 + 1, c0 + 2, c0 + 3, c1, c1 + 1};
  float s = 0.f, q = 0.f;
#pragma unroll
  for (int i = 0; i < 6; i++) { s += v[i]; q += v[i] * v[i]; }
#pragma unroll
  for (int m = 1; m < 64; m <<= 1) { s += __shfl_xor(s, m); q += __shfl_xor(q, m); }
  float mean = s * (1.f / 384.f);
  float rstd = rsqrtf(q * (1.f / 384.f) - mean * mean + 1e-5f);
  float y1[6];
  s = 0.f; q = 0.f;
#pragma unroll
  for (int i = 0; i < 6; i++) {
    y1[i] = (v[i] - mean) * rstd * g2[ch[i]] + b2[ch[i]];
    s += y1[i]; q += y1[i] * y1[i];
  }
#pragma unroll
  for (int m = 1; m < 64; m <<= 1) { s += __shfl_xor(s, m); q += __shfl_xor(q, m); }
  float m2 = s * (1.f / 384.f);
  float r2 = rsqrtf(q * (1.f / 384.f) - m2 * m2 + 1e-6f);
  __hip_bfloat16* o = yln + (size_t)t * 384;
#pragma unroll
  for (int i = 0; i < 6; i++)
    o[ch[i]] = __float2bfloat16((y1[i] - m2) * r2 * gf[ch[i]] + bf_[ch[i]]);
}

// ---------- 4-phase, triple-buffered, counted-vmcnt bf16 MFMA GEMM ----------
// C(M,N) = A(M,K) @ Wt(N,K)^T + bias.
// BM=256 BN=128 BK=64, 512 thr / 8 waves (4M x 2N), wave-tile 64x64.
// LDS: 3 bufs x (A 32KB + B 16KB) = 144KB -> 1 block/CU (by design, m201-style).
// Swizzle: 16B chunk c within a 128B row stored at slot c^(row&7) (pre-swizzled
// global source, linear gload_lds dest, same XOR on ds_read) -> 2 lanes/bank.
// vmcnt(6) steady state (stage 2 K-steps ahead), vmcnt(0) only on last step.
// CRITICAL (R5 lesson): vmcnt wait must be followed by s_barrier BEFORE any
// ds_read of the staged buffer — vmcnt is per-wave; the barrier publishes.
enum { EPI_QKV = 0, EPI_PROJ = 1, EPI_FF1 = 2, EPI_FF2 = 3 };

#define STG_A(SB, J, SOFF) \
  gload_lds16(PA + (size_t)(J) * 64 * K + (SOFF), &LB[(SB) * 24576 + ((J) * 512 + w * 64) * 8])
#define STG_B(SB, J, SOFF) \
  gload_lds16(PB + (size_t)(J) * 64 * K + (SOFF), &LB[(SB) * 24576 + 16384 + ((J) * 512 + w * 64) * 8])

#define MFMA8(NIA, NIB)                                                       \
  __builtin_amdgcn_s_setprio(1);                                              \
  _Pragma("unroll") for (int mi = 0; mi < 4; mi++) {                          \
    acc[mi][NIA] = __builtin_amdgcn_mfma_f32_16x16x32_bf16(af[mi], bf[NIA],   \
                                                           acc[mi][NIA], 0, 0, 0); \
    acc[mi][NIB] = __builtin_amdgcn_mfma_f32_16x16x32_bf16(af[mi], bf[NIB],   \
                                                           acc[mi][NIB], 0, 0, 0); \
  }                                                                           \
  __builtin_amdgcn_s_setprio(0);

#define STEP(CB, SB, TS)                                                      \
  {                                                                           \
    if ((TS) - 1 < ntiles)                                                    \
      asm volatile("s_waitcnt vmcnt(6)" ::: "memory");                        \
    else                                                                      \
      asm volatile("s_waitcnt vmcnt(0)" ::: "memory");                        \
    __builtin_amdgcn_s_barrier(); /* publish: buf CB staged by ALL waves */   \
    const bool dost = (TS) < ntiles;                                          \
    const int soff = (TS) * 64;                                               \
    const __hip_bfloat16* lb = &LB[(CB) * 24576];                             \
    /* phase 0: A frags kk0 + B frags 0,1 kk0; stage A passes 0,1 */          \
    af[0] = *(const bf16x8*)(lb + aK0);                                       \
    af[1] = *(const bf16x8*)(lb + aK0 + 1024);                                \
    af[2] = *(const bf16x8*)(lb + aK0 + 2048);                                \
    af[3] = *(const bf16x8*)(lb + aK0 + 3072);                                \
    bf[0] = *(const bf16x8*)(lb + bK0);                                       \
    bf[1] = *(const bf16x8*)(lb + bK0 + 1024);                                \
    if (dost) { STG_A(SB, 0, soff); STG_A(SB, 1, soff); }                     \
    __builtin_amdgcn_s_barrier();                                             \
    MFMA8(0, 1)                                                               \
    __builtin_amdgcn_s_barrier();                                             \
    /* phase 1: B frags 2,3 kk0; stage A passes 2,3 */                        \
    bf[2] = *(const bf16x8*)(lb + bK0 + 2048);                                \
    bf[3] = *(const bf16x8*)(lb + bK0 + 3072);                                \
    if (dost) { STG_A(SB, 2, soff); STG_A(SB, 3, soff); }                     \
    __builtin_amdgcn_s_barrier();                                             \
    MFMA8(2, 3)                                                               \
    __builtin_amdgcn_s_barrier();                                             \
    /* phase 2: A frags kk1 + B frags 0,1 kk1; stage B pass 0 */              \
    af[0] = *(const bf16x8*)(lb + (aK0 ^ 32));                                \
    af[1] = *(const bf16x8*)(lb + (aK0 ^ 32) + 1024);                         \
    af[2] = *(const bf16x8*)(lb + (aK0 ^ 32) + 2048);                         \
    af[3] = *(const bf16x8*)(lb + (aK0 ^ 32) + 3072);                         \
    bf[0] = *(const bf16x8*)(lb + (bK0 ^ 32));                                \
    bf[1] = *(const bf16x8*)(lb + (bK0 ^ 32) + 1024);                         \
    if (dost) { STG_B(SB, 0, soff); }                                         \
    __builtin_amdgcn_s_barrier();                                             \
    MFMA8(0, 1)                                                               \
    __builtin_amdgcn_s_barrier();                                             \
    /* phase 3: B frags 2,3 kk1; stage B pass 1 */                            \
    bf[2] = *(const bf16x8*)(lb + (bK0 ^ 32) + 2048);                         \
    bf[3] = *(const bf16x8*)(lb + (bK0 ^ 32) + 3072);                         \
    if (dost) { STG_B(SB, 1, soff); }                                         \
    __builtin_amdgcn_s_barrier();                                             \
    MFMA8(2, 3)                                                               \
    __builtin_amdgcn_s_barrier();                                             \
  }

template <int EPI>
__global__ __launch_bounds__(512, 1)
void k_gemm(const __hip_bfloat16* __restrict__ A, const __hip_bfloat16* __restrict__ Wt,
            const float* __restrict__ bias, int K, int nCol, int cpx,
            const float* __restrict__ aux,        // PROJ: x; FF2: x_res
            float* __restrict__ out_f,            // PROJ: x_res; FF2: final out
            __hip_bfloat16* __restrict__ out_b) { // QKV: q base; FF1: hbuf
  __shared__ __hip_bfloat16 LB[3 * 24576];        // 144 KiB
  int tid = threadIdx.x;
  int lane = tid & 63, w = tid >> 6;
  int g = lane >> 4, r16 = lane & 15;
  int wr = w >> 1, wc = w & 1;  // wave grid 4(M) x 2(N)

  int bid = blockIdx.x;
  int wg = (bid & 7) * cpx + (bid >> 3);   // XCD swizzle (nwg % 8 == 0)
  int rB = wg / nCol;
  int rowBlk = rB * 256;
  int colBlk = (wg - rB * nCol) * 128;

  // staging: pass j covers LDS 16B-slots j*512 + tid; row = slot>>3, in-row
  // slot lane&7 holds global chunk (lane&7)^(row&7), row&7 == lane>>3.
  int rA0 = w * 8 + (lane >> 3);
  int cch = (lane & 7) ^ (lane >> 3);
  const __hip_bfloat16* PA = A + (size_t)(rowBlk + rA0) * K + cch * 8;
  const __hip_bfloat16* PB = Wt + (size_t)(colBlk + rA0) * K + cch * 8;

  // read offsets (elements): row*64 + (chunk ^ (row&7))*8; row&7 == r16&7.
  int sw0 = (g ^ (r16 & 7)) * 8;
  int aK0 = (wr * 64 + r16) * 64 + sw0;            // + mi*1024; kk1 = ^32
  int bK0 = 16384 + (wc * 64 + r16) * 64 + sw0;    // + ni*1024; kk1 = ^32

  bf16x8 af[4], bf[4];
  f32x4 acc[4][4] = {};
  const int ntiles = K >> 6;   // 6 or 24, divisible by 3

  // prologue: stage steps 0 (buf0) and 1 (buf1)
  STG_A(0, 0, 0); STG_A(0, 1, 0); STG_A(0, 2, 0); STG_A(0, 3, 0);
  STG_B(0, 0, 0); STG_B(0, 1, 0);
  STG_A(1, 0, 64); STG_A(1, 1, 64); STG_A(1, 2, 64); STG_A(1, 3, 64);
  STG_B(1, 0, 64); STG_B(1, 1, 64);

  for (int t = 0; t < ntiles; t += 3) {
    STEP(0, 2, t + 2)
    STEP(1, 0, t + 3)
    STEP(2, 1, t + 4)
  }

#pragma unroll
  for (int mi = 0; mi < 4; mi++) {
#pragma unroll
    for (int rr = 0; rr < 4; rr++) {
      int row = rowBlk + wr * 64 + mi * 16 + g * 4 + rr;
      int winr = 0, nn = 0; size_t nt2 = 0;
      if constexpr (EPI == EPI_QKV) { winr = row / 49; nn = row - winr * 49; }
      if constexpr (EPI == EPI_PROJ) { nt2 = win_to_nat(row); }
#pragma unroll
      for (int ni = 0; ni < 4; ni++) {
        int col = colBlk + wc * 64 + ni * 16 + r16;
        float val = acc[mi][ni][rr] + bias[col];
        if constexpr (EPI == EPI_QKV) {
          int which = col / 384; int rem = col - which * 384;
          int hh = rem >> 5, dd = rem & 31;
          size_t off = (((size_t)winr * 12 + hh) * 49 + nn) * 32 + dd;
          out_b[(size_t)which * 38535168u + off] = __float2bfloat16(val);
        } else if constexpr (EPI == EPI_PROJ) {
          out_f[nt2 * 384 + col] = val + aux[nt2 * 384 + col];
        } else if constexpr (EPI == EPI_FF1) {
          // tanh-form gelu (max |diff| vs erf-gelu ~1e-3)
          float u = val * (val * val * 0.044715f + 1.0f) * 1.5957691216f;
          float e = __expf(u);
          float th = 1.f - 2.f / (e + 1.f);
          float ge = 0.5f * val * (1.f + th);
          out_b[(size_t)row * 1536 + col] = __float2bfloat16(ge);
        } else {
          out_f[(size_t)row * 384 + col] = val + aux[(size_t)row * 384 + col];
        }
      }
    }
  }
}

// ---------- windowed attention: 1 wave per (window, head) ----------
__global__ __launch_bounds__(256)
void k_attn(const __hip_bfloat16* __restrict__ q, const __hip_bfloat16* __restrict__ k,
            const __hip_bfloat16* __restrict__ v, const float* __restrict__ rpb,
            __hip_bfloat16* __restrict__ o) {
  __shared__ __hip_bfloat16 P[4][64][72];
  int tid = threadIdx.x;
  int lane = tid & 63, wave = tid >> 6;
  int g = lane >> 4, r16 = lane & 15;
  int gid = blockIdx.x * 4 + wave;              // 0..24575 window-heads
  int wi = gid / 12, h = gid - (gid / 12) * 12;
  int wimg = wi & 63;
  int hb = wimg >> 3, wb = wimg & 7;
  size_t base = ((size_t)wi * 12 + h) * (49 * 32);
  const __hip_bfloat16* qb = q + base;
  const __hip_bfloat16* kb = k + base;
  const __hip_bfloat16* vb = v + base;

  bf16x8 zf = {0, 0, 0, 0, 0, 0, 0, 0};
  bf16x8 qf[4], kf[4];
#pragma unroll
  for (int mi = 0; mi < 4; mi++) {
    int row = mi * 16 + r16;
    qf[mi] = (row < 49) ? *(const bf16x8*)(qb + row * 32 + g * 8) : zf;
    kf[mi] = (row < 49) ? *(const bf16x8*)(kb + row * 32 + g * 8) : zf;
  }
  f32x4 fz = {0.f, 0.f, 0.f, 0.f};
  f32x4 S[4][4];
#pragma unroll
  for (int mi = 0; mi < 4; mi++)
#pragma unroll
    for (int ni = 0; ni < 4; ni++)
      S[mi][ni] = __builtin_amdgcn_mfma_f32_16x16x32_bf16(qf[mi], kf[ni], fz, 0, 0, 0);

  int kiA[4], kjA[4], rkA[4], cvA[4];
#pragma unroll
  for (int ni = 0; ni < 4; ni++) {
    int col = ni * 16 + r16;
    cvA[ni] = (col < 49);
    int ki = col / 7, kj = col - (col / 7) * 7;
    kiA[ni] = ki; kjA[ni] = kj;
    int hg = hb * 7 + ki, wg = wb * 7 + kj;
    int rh = (hg < 49) ? 0 : ((hg < 53) ? 1 : 2);
    int rw = (wg < 49) ? 0 : ((wg < 53) ? 1 : 2);
    rkA[ni] = rh * 3 + rw;
  }

#pragma unroll
  for (int mi = 0; mi < 4; mi++) {
#pragma unroll
    for (int rr = 0; rr < 4; rr++) {
      int row = mi * 16 + g * 4 + rr;
      float sv[4];
      float mx = -1e30f;
      int qi = row / 7, qj = row - (row / 7) * 7;
      int hgq = hb * 7 + qi, wgq = wb * 7 + qj;
      int rhq = (hgq < 49) ? 0 : ((hgq < 53) ? 1 : 2);
      int rwq = (wgq < 49) ? 0 : ((wgq < 53) ? 1 : 2);
      int rq = rhq * 3 + rwq;
#pragma unroll
      for (int ni = 0; ni < 4; ni++) {
        float s = -1e30f;
        if (row < 49 && cvA[ni]) {
          int idx = (qi - kiA[ni] + 6) * 13 + (qj - kjA[ni] + 6);
          float maskv = (rq != rkA[ni]) ? -100.f : 0.f;
          s = S[mi][ni][rr] * SCALE + rpb[idx * 12 + h] + maskv;
        }
        sv[ni] = s;
        mx = fmaxf(mx, s);
      }
#pragma unroll
      for (int m = 1; m <= 8; m <<= 1) mx = fmaxf(mx, __shfl_xor(mx, m));
      float sum = 0.f;
#pragma unroll
      for (int ni = 0; ni < 4; ni++) {
        float p = __expf(sv[ni] - mx);
        sv[ni] = p; sum += p;
      }
#pragma unroll
      for (int m = 1; m <= 8; m <<= 1) sum += __shfl_xor(sum, m);
      float inv = 1.f / sum;
#pragma unroll
      for (int ni = 0; ni < 4; ni++)
        P[wave][row][ni * 16 + r16] = __float2bfloat16(sv[ni] * inv);
    }
  }

  f32x4 O[4][2] = {};
#pragma unroll
  for (int ks = 0; ks < 2; ks++) {
    bf16x8 pf[4];
#pragma unroll
    for (int mi = 0; mi < 4; mi++)
      pf[mi] = *(const bf16x8*)(&P[wave][mi * 16 + r16][ks * 32 + g * 8]);
#pragma unroll
    for (int ni = 0; ni < 2; ni++) {
      bf16x8 vf = zf;
#pragma unroll
      for (int j = 0; j < 8; j++) {
        int m = ks * 32 + g * 8 + j;
        if (m < 49) vf[j] = ((const short*)vb)[m * 32 + ni * 16 + r16];
      }
#pragma unroll
      for (int mi = 0; mi < 4; mi++)
        O[mi][ni] = __builtin_amdgcn_mfma_f32_16x16x32_bf16(pf[mi], vf, O[mi][ni], 0, 0, 0);
    }
  }

#pragma unroll
  for (int mi = 0; mi < 4; mi++)
#pragma unroll
    for (int rr = 0; rr < 4; rr++) {
      int row = mi * 16 + g * 4 + rr;
      if (row < 49) {
#pragma unroll
        for (int ni = 0; ni < 2; ni++) {
          int col = ni * 16 + r16;
          o[(((size_t)wi * 49 + row) * 12 + h) * 32 + col] = __float2bfloat16(O[mi][ni][rr]);
        }
      }
    }
}

// ---------- host launch ----------
extern "C" void kernel_launch(void* const* d_in, const int* in_sizes, int n_in,
                              void* d_out, int out_size, void* d_ws, size_t ws_size,
                              hipStream_t stream) {
  const float* x      = (const float*)d_in[0];
  const float* ln1_g  = (const float*)d_in[1];
  const float* ln1_b  = (const float*)d_in[2];
  const float* qkv_w  = (const float*)d_in[3];
  const float* qkv_b  = (const float*)d_in[4];
  const float* proj_w = (const float*)d_in[5];
  const float* proj_b = (const float*)d_in[6];
  const float* rpb    = (const float*)d_in[7];
  const float* ln2_g  = (const float*)d_in[8];
  const float* ln2_b  = (const float*)d_in[9];
  const float* ffg    = (const float*)d_in[10];
  const float* ffb    = (const float*)d_in[11];
  const float* ff1_w  = (const float*)d_in[12];
  const float* ff1_b  = (const float*)d_in[13];
  const float* ff2_w  = (const float*)d_in[14];
  const float* ff2_b  = (const float*)d_in[15];
  float* out = (float*)d_out;

  char* ws = (char*)d_ws;
  __hip_bfloat16* xw     = (__hip_bfloat16*)ws;
  __hip_bfloat16* qbuf   = (__hip_bfloat16*)(ws + 77070336u);
  __hip_bfloat16* kbuf   = qbuf + 38535168u;
  __hip_bfloat16* vbuf   = kbuf + 38535168u;
  __hip_bfloat16* attn_o = xw;
  __hip_bfloat16* hbuf   = (__hip_bfloat16*)ws;
  float*          x_res  = (float*)(ws + 308281344u);
  __hip_bfloat16* yln    = (__hip_bfloat16*)(ws + 462422016u);
  __hip_bfloat16* qkv_wt = (__hip_bfloat16*)(ws + 539492352u);
  __hip_bfloat16* proj_wt = qkv_wt + 442368u;
  __hip_bfloat16* ff1_wt  = proj_wt + 147456u;
  __hip_bfloat16* ff2_wt  = ff1_wt + 589824u;

  // weight prep (tiled transpose: K/32 x N/32 tiles)
  k_transpose<<<dim3(1152 / 32, 384 / 32), dim3(256), 0, stream>>>(qkv_w, qkv_wt, 384, 1152);
  k_transpose<<<dim3(384 / 32, 384 / 32), dim3(256), 0, stream>>>(proj_w, proj_wt, 384, 384);
  k_transpose<<<dim3(1536 / 32, 384 / 32), dim3(256), 0, stream>>>(ff1_w, ff1_wt, 384, 1536);
  k_transpose<<<dim3(384 / 32, 1536 / 32), dim3(256), 0, stream>>>(ff2_w, ff2_wt, 1536, 384);

  // LN1 + shift + window partition
  k_ln1<<<dim3(25088), dim3(256), 0, stream>>>(x, ln1_g, ln1_b, xw);

  // GEMMs: BM=256, BN=128. M blocks = 100352/256 = 392.
  // QKV: nCol = 1152/128 = 9 -> nwg 3528
  k_gemm<EPI_QKV><<<dim3(3528), dim3(512), 0, stream>>>(xw, qkv_wt, qkv_b, 384, 9, 3528 / 8,
                                                        nullptr, nullptr, qbuf);
  // attention: 24576 window-heads, 4 per block
  k_attn<<<dim3(6144), dim3(256), 0, stream>>>(qbuf, kbuf, vbuf, rpb, attn_o);
  // proj: nCol = 3 -> nwg 1176
  k_gemm<EPI_PROJ><<<dim3(1176), dim3(512), 0, stream>>>(attn_o, proj_wt, proj_b, 384, 3, 1176 / 8,
                                                         x, x_res, nullptr);
  // LN2 + ffLN
  k_ln2ff<<<dim3(25088), dim3(256), 0, stream>>>(x_res, ln2_g, ln2_b, ffg, ffb, yln);
  // FF1 + gelu: nCol = 12 -> nwg 4704
  k_gemm<EPI_FF1><<<dim3(4704), dim3(512), 0, stream>>>(yln, ff1_wt, ff1_b, 384, 12, 4704 / 8,
                                                        nullptr, nullptr, hbuf);
  // FF2 + residual -> out: K=1536, nCol = 3 -> nwg 1176
  k_gemm<EPI_FF2><<<dim3(1176), dim3(512), 0, stream>>>(hbuf, ff2_wt, ff2_b, 1536, 3, 1176 / 8,
                                                        x_res, out, nullptr);
}